// Round 1
// baseline (3207.940 us; speedup 1.0000x reference)
//
#include <hip/hip_runtime.h>
#include <hip/hip_bf16.h>

#define DD 1024
#define MDD 256
#define LL 2048
#define BB 4
#define NROWS (BB*LL)   // 8192

typedef short bf16x8 __attribute__((ext_vector_type(8)));
typedef float f32x4 __attribute__((ext_vector_type(4)));

__device__ __forceinline__ short f2b(float x){
  __hip_bfloat16 h = __float2bfloat16(x);
  return *reinterpret_cast<short*>(&h);
}
__device__ __forceinline__ float b2f(short s){
  return __uint_as_float(((unsigned)(unsigned short)s) << 16);
}

// ---------------- weight conversion ----------------
__global__ void cvt_submat(const float* __restrict__ src, short* __restrict__ dst,
                           int rows, int cols, int src_ld, int src_off){
  int n = rows*cols;
  for (int i = blockIdx.x*blockDim.x + threadIdx.x; i < n; i += gridDim.x*blockDim.x){
    int r = i / cols, c = i - r*cols;
    dst[i] = f2b(src[(size_t)r*src_ld + src_off + c]);
  }
}

__global__ void concat3(const float* __restrict__ a, int na,
                        const float* __restrict__ b, int nb,
                        const float* __restrict__ c, int nc,
                        float* __restrict__ dst){
  int i = blockIdx.x*blockDim.x + threadIdx.x;
  if (i < na) dst[i] = a[i];
  else if (i < na+nb) dst[i] = b[i-na];
  else if (i < na+nb+nc) dst[i] = c[i-na-nb];
}

// ---------------- rmsnorm (f32 in -> bf16 out) ----------------
__global__ __launch_bounds__(256) void rmsnorm_k(const float* __restrict__ x,
                                                 const float* __restrict__ w,
                                                 short* __restrict__ xn){
  int row = blockIdx.x, tid = threadIdx.x;
  const float* xr = x + (size_t)row*DD;
  float4 v = *(const float4*)&xr[tid*4];
  float ss = v.x*v.x + v.y*v.y + v.z*v.z + v.w*v.w;
  __shared__ float red[256];
  red[tid] = ss; __syncthreads();
  for (int s = 128; s > 0; s >>= 1){ if (tid < s) red[tid] += red[tid+s]; __syncthreads(); }
  float scale = rsqrtf(red[0]/(float)DD + 1e-6f);
  const float* wr = w + tid*4;
  short4 o;
  o.x = f2b(v.x*wr[0]*scale); o.y = f2b(v.y*wr[1]*scale);
  o.z = f2b(v.z*wr[2]*scale); o.w = f2b(v.w*wr[3]*scale);
  *(short4*)&xn[(size_t)row*DD + tid*4] = o;
}

// ---------------- depthwise causal conv K=5 ----------------
__global__ __launch_bounds__(256) void dwconv_k(const short* __restrict__ xn,
                                                const float* __restrict__ dwk,
                                                const float* __restrict__ dwb,
                                                short* __restrict__ xc){
  size_t i = (size_t)blockIdx.x*256 + threadIdx.x;  // over NROWS*DD
  int d = (int)(i & (DD-1));
  int l = (int)((i >> 10) & (LL-1));
  int b = (int)(i >> 21);
  float acc = dwb[d];
  const float* kk = dwk + d*5;
  #pragma unroll
  for (int k = 0; k < 5; ++k){
    int ll = l + k - 4;
    if (ll >= 0) acc += b2f(xn[((size_t)(b*LL + ll) << 10) + d]) * kk[k];
  }
  xc[i] = f2b(acc);
}

// ---------------- generic bf16 MFMA GEMM: C = act(A @ Bw^T + bias) (+adds) ----------------
// A: (M,K) bf16 row-major; Bw: (N,K) bf16 row-major.
// OUTMODE: 0=f32 store, 1=f32 accumulate, 2=bf16 store. ACT: 0 none,1 silu,2 exact gelu.
template<int ACT, int OUTMODE, int PERMUTE>
__global__ __launch_bounds__(256) void gemm_bt(
    const short* __restrict__ A, const short* __restrict__ Bw,
    const float* __restrict__ bias, const float* __restrict__ add0,
    const float* __restrict__ add1, void* __restrict__ Cout,
    int M, int N, int K, int nbn){
  __shared__ __align__(16) short As[128*56];
  __shared__ __align__(16) short Bs[128*56];
  int bm = blockIdx.x / nbn, bn = blockIdx.x % nbn;
  int tid = threadIdx.x, lane = tid & 63, w = tid >> 6;
  int wm = (w >> 1)*64, wn = (w & 1)*64;
  const int r0 = lane & 15, kg = lane >> 4;

  f32x4 acc[4][4];
  #pragma unroll
  for (int i = 0; i < 4; ++i)
    #pragma unroll
    for (int j = 0; j < 4; ++j)
      #pragma unroll
      for (int r = 0; r < 4; ++r) acc[i][j][r] = 0.f;

  for (int k0 = 0; k0 < K; k0 += 32){
    for (int c = tid; c < 512; c += 256){
      int row = c >> 2, seg = c & 3;
      *(bf16x8*)&As[row*56 + seg*8] = *(const bf16x8*)&A[(size_t)(bm*128 + row)*K + k0 + seg*8];
      *(bf16x8*)&Bs[row*56 + seg*8] = *(const bf16x8*)&Bw[(size_t)(bn*128 + row)*K + k0 + seg*8];
    }
    __syncthreads();
    bf16x8 av[4], bv[4];
    #pragma unroll
    for (int i = 0; i < 4; ++i) av[i] = *(const bf16x8*)&As[(wm + i*16 + r0)*56 + kg*8];
    #pragma unroll
    for (int j = 0; j < 4; ++j) bv[j] = *(const bf16x8*)&Bs[(wn + j*16 + r0)*56 + kg*8];
    #pragma unroll
    for (int i = 0; i < 4; ++i)
      #pragma unroll
      for (int j = 0; j < 4; ++j)
        acc[i][j] = __builtin_amdgcn_mfma_f32_16x16x32_bf16(av[i], bv[j], acc[i][j], 0, 0, 0);
    __syncthreads();
  }

  #pragma unroll
  for (int i = 0; i < 4; ++i){
    int grb = bm*128 + wm + i*16 + kg*4;
    #pragma unroll
    for (int j = 0; j < 4; ++j){
      int gc = bn*128 + wn + j*16 + r0;
      float bvv = bias ? bias[gc] : 0.f;
      #pragma unroll
      for (int r = 0; r < 4; ++r){
        int gr = grb + r;
        float v = acc[i][j][r] + bvv;
        if (ACT == 1) v = v / (1.f + __expf(-v));
        else if (ACT == 2) v = 0.5f*v*(1.f + erff(v*0.70710678118f));
        size_t orow = PERMUTE ? (size_t)((gr & 3)*LL + (gr >> 2)) : (size_t)gr;
        size_t oi = orow*(size_t)N + gc;
        if (add0) v += add0[oi];
        if (add1) v += add1[oi];
        if (OUTMODE == 0) ((float*)Cout)[oi] = v;
        else if (OUTMODE == 1) ((float*)Cout)[oi] += v;
        else ((short*)Cout)[oi] = f2b(v);
      }
    }
  }
}

// ---------------- f32 -> bf16 bulk convert ----------------
__global__ __launch_bounds__(256) void f2b_k(const float* __restrict__ src,
                                             short* __restrict__ dst, int n4){
  int i = blockIdx.x*256 + threadIdx.x;
  if (i < n4){
    float4 v = *(const float4*)&src[(size_t)i*4];
    short4 o; o.x = f2b(v.x); o.y = f2b(v.y); o.z = f2b(v.z); o.w = f2b(v.w);
    *(short4*)&dst[(size_t)i*4] = o;
  }
}

// ---------------- sequential recurrence (1 block, 8 waves) ----------------
// fxu rows = b*LL + t, 768 cols: [0,256)=fx, [256,512)=ux, [512,768)=xm_raw.
// Wfu: (512,256) bf16 = [Wf_m ; Wu_m]. m2all rows = t*4+b (bf16).
__global__ __launch_bounds__(512) void scan_k(
    const float* __restrict__ fxu, const short* __restrict__ Wfu,
    const float* __restrict__ m0, short* __restrict__ m2all,
    float* __restrict__ newmem){
  __shared__ __align__(16) short mA[16*264];   // bf16 A-tile, rows 4..15 stay zero
  __shared__ float mF[1024];                   // f32 master state, b*256+j
  __shared__ float gates[4*520];               // raw logits per batch
  __shared__ float fbuf[2][3072];              // double-buffered fxu tile (4x768)
  const int tid = threadIdx.x, lane = tid & 63, w = tid >> 6;
  const int r0 = lane & 15, kg = lane >> 4;

  for (int i = tid; i < 16*264; i += 512) mA[i] = 0;
  for (int i = tid; i < 1024; i += 512) mF[i] = m0[i];
  {
    int b = tid >> 7, c0 = tid & 127;
    #pragma unroll
    for (int q = 0; q < 6; ++q)
      fbuf[0][b*768 + c0 + q*128] = fxu[(size_t)(b*LL)*768 + c0 + q*128];
  }
  // preload gate weights into registers (B-fragments), 4 n-tiles per wave
  bf16x8 bw[4][8];
  #pragma unroll
  for (int n4 = 0; n4 < 4; ++n4)
    #pragma unroll
    for (int kt = 0; kt < 8; ++kt)
      bw[n4][kt] = *(const bf16x8*)&Wfu[(size_t)(w*64 + n4*16 + r0)*256 + kt*32 + kg*8];
  __syncthreads();
  for (int i = tid; i < 1024; i += 512){
    int b = i >> 8, j = i & 255;
    mA[b*264 + j] = f2b(mF[i]);
  }
  __syncthreads();

  int cur = 0;
  const int pb = tid >> 7, pc = tid & 127;
  for (int t = 0; t < LL; ++t){
    // prefetch next step's fxu tile into registers (hidden under MFMAs)
    float pf[6];
    if (t + 1 < LL){
      #pragma unroll
      for (int q = 0; q < 6; ++q)
        pf[q] = fxu[(size_t)(pb*LL + t + 1)*768 + pc + q*128];
    }
    // A-fragments from LDS (m state, bf16)
    bf16x8 af[8];
    #pragma unroll
    for (int kt = 0; kt < 8; ++kt)
      af[kt] = *(const bf16x8*)&mA[r0*264 + kt*32 + kg*8];
    // gate logits via MFMA
    #pragma unroll
    for (int n4 = 0; n4 < 4; ++n4){
      f32x4 acc; acc[0]=0.f; acc[1]=0.f; acc[2]=0.f; acc[3]=0.f;
      #pragma unroll
      for (int kt = 0; kt < 8; ++kt)
        acc = __builtin_amdgcn_mfma_f32_16x16x32_bf16(af[kt], bw[n4][kt], acc, 0, 0, 0);
      if (kg == 0){
        int n = w*64 + n4*16 + r0;
        #pragma unroll
        for (int r = 0; r < 4; ++r) gates[r*520 + n] = acc[r];
      }
    }
    __syncthreads();
    // state update
    #pragma unroll
    for (int p = 0; p < 2; ++p){
      int idx = tid + p*512;
      int b = idx >> 8, j = idx & 255;
      float fr = gates[b*520 + j]        + fbuf[cur][b*768 + j];
      float ur = gates[b*520 + 256 + j]  + fbuf[cur][b*768 + 256 + j];
      float f = 1.f/(1.f + __expf(-fr));
      float u = 1.f/(1.f + __expf(-ur));
      float xmr = fbuf[cur][b*768 + 512 + j];
      float xm = xmr / (1.f + __expf(-xmr));
      float m2 = f*mF[idx] + u*xm;
      mF[idx] = m2;
      short mb = f2b(m2);
      mA[b*264 + j] = mb;
      m2all[(size_t)(t*4 + b)*256 + j] = mb;
    }
    if (t + 1 < LL){
      #pragma unroll
      for (int q = 0; q < 6; ++q)
        fbuf[cur ^ 1][pb*768 + pc + q*128] = pf[q];
    }
    __syncthreads();
    cur ^= 1;
  }
  for (int i = tid; i < 1024; i += 512) newmem[i] = mF[i];
}

// ---------------- router + expert combine + final rmsnorm ----------------
__global__ __launch_bounds__(256) void combine_k(
    float* __restrict__ y, const short* __restrict__ e0, const short* __restrict__ e1,
    const float* __restrict__ rw, const float* __restrict__ rb,
    const float* __restrict__ fw, short* __restrict__ y2bf){
  int row = blockIdx.x, tid = threadIdx.x;
  size_t base = (size_t)row*DD + tid*4;
  float4 vy = *(const float4*)&y[base];
  short4 s0 = *(const short4*)&e0[base];
  short4 s1 = *(const short4*)&e1[base];
  float4 w0 = *(const float4*)&rw[tid*4];
  float4 w1 = *(const float4*)&rw[DD + tid*4];
  float d0 = vy.x*w0.x + vy.y*w0.y + vy.z*w0.z + vy.w*w0.w;
  float d1 = vy.x*w1.x + vy.y*w1.y + vy.z*w1.z + vy.w*w1.w;
  __shared__ float redA[256], redB[256];
  redA[tid] = d0; redB[tid] = d1; __syncthreads();
  for (int s = 128; s > 0; s >>= 1){
    if (tid < s){ redA[tid] += redA[tid+s]; redB[tid] += redB[tid+s]; }
    __syncthreads();
  }
  float l0 = redA[0] + rb[0], l1 = redB[0] + rb[1];
  float p0 = 1.f/(1.f + __expf(l1 - l0));
  float p1 = 1.f - p0;
  float c0 = vy.x + p0*b2f(s0.x) + p1*b2f(s1.x);
  float c1 = vy.y + p0*b2f(s0.y) + p1*b2f(s1.y);
  float c2 = vy.z + p0*b2f(s0.z) + p1*b2f(s1.z);
  float c3 = vy.w + p0*b2f(s0.w) + p1*b2f(s1.w);
  float ss = c0*c0 + c1*c1 + c2*c2 + c3*c3;
  __syncthreads();
  redA[tid] = ss; __syncthreads();
  for (int s = 128; s > 0; s >>= 1){
    if (tid < s) redA[tid] += redA[tid+s];
    __syncthreads();
  }
  float scale = rsqrtf(redA[0]/(float)DD + 1e-6f);
  const float* fwp = fw + tid*4;
  float o0 = c0*fwp[0]*scale, o1 = c1*fwp[1]*scale, o2 = c2*fwp[2]*scale, o3 = c3*fwp[3]*scale;
  float4 ov; ov.x = o0; ov.y = o1; ov.z = o2; ov.w = o3;
  *(float4*)&y[base] = ov;
  short4 ob; ob.x = f2b(o0); ob.y = f2b(o1); ob.z = f2b(o2); ob.w = f2b(o3);
  *(short4*)&y2bf[base] = ob;
}

// ---------------- host ----------------
extern "C" void kernel_launch(void* const* d_in, const int* in_sizes, int n_in,
                              void* d_out, int out_size, void* d_ws, size_t ws_size,
                              hipStream_t stream){
  (void)in_sizes; (void)n_in; (void)out_size; (void)ws_size;
  const float* x     = (const float*)d_in[0];
  const float* mem0  = (const float*)d_in[1];
  const float* normw = (const float*)d_in[2];
  const float* dwk   = (const float*)d_in[3];
  const float* dwb   = (const float*)d_in[4];
  const float* pw    = (const float*)d_in[5];
  const float* pwb   = (const float*)d_in[6];
  const float* Win_w = (const float*)d_in[7];
  const float* Win_b = (const float*)d_in[8];
  const float* Wf_w  = (const float*)d_in[9];
  const float* Wf_b  = (const float*)d_in[10];
  const float* Wu_w  = (const float*)d_in[11];
  const float* Wu_b  = (const float*)d_in[12];
  const float* Wo_w  = (const float*)d_in[13];
  const float* Wo_b  = (const float*)d_in[14];
  const float* rw    = (const float*)d_in[15];
  const float* rb    = (const float*)d_in[16];
  const float* e0w1  = (const float*)d_in[17];
  const float* e0b1  = (const float*)d_in[18];
  const float* e0w2  = (const float*)d_in[19];
  const float* e0b2  = (const float*)d_in[20];
  const float* e1w1  = (const float*)d_in[21];
  const float* e1b1  = (const float*)d_in[22];
  const float* e1w2  = (const float*)d_in[23];
  const float* e1b2  = (const float*)d_in[24];
  const float* fnw   = (const float*)d_in[25];
  const float* dnw   = (const float*)d_in[26];
  const float* dnb   = (const float*)d_in[27];
  const float* upw   = (const float*)d_in[28];
  const float* upb   = (const float*)d_in[29];

  char* ws = (char*)d_ws;
  size_t off = 0;
  auto alloc = [&](size_t bytes)->char*{
    char* p = ws + off; off += (bytes + 255) & ~(size_t)255; return p;
  };
  short* W_pw     = (short*)alloc((size_t)1024*1024*2);
  short* W_fxuwin = (short*)alloc((size_t)768*1024*2);
  short* W_ox     = (short*)alloc((size_t)1024*1024*2);
  short* W_fum    = (short*)alloc((size_t)512*256*2);
  short* W_om     = (short*)alloc((size_t)1024*256*2);
  short* W_e0w1   = (short*)alloc((size_t)1024*1024*2);
  short* W_e0w2   = (short*)alloc((size_t)1024*1024*2);
  short* W_e1w1   = (short*)alloc((size_t)1024*1024*2);
  short* W_e1w2   = (short*)alloc((size_t)1024*1024*2);
  short* W_down   = (short*)alloc((size_t)256*1024*2);
  short* W_up     = (short*)alloc((size_t)1024*256*2);
  float* bias768  = (float*)alloc(768*4);
  short* xn       = (short*)alloc((size_t)NROWS*DD*2);
  short* xc       = (short*)alloc((size_t)NROWS*DD*2);
  float* fxu      = (float*)alloc((size_t)NROWS*768*4);
  float* ybuf     = (float*)alloc((size_t)NROWS*DD*4);
  short* m2all    = (short*)alloc((size_t)NROWS*MDD*2);
  short* ybf      = (short*)alloc((size_t)NROWS*DD*2);
  short* e0v      = (short*)alloc((size_t)NROWS*DD*2);
  short* e1v      = (short*)alloc((size_t)NROWS*DD*2);
  short* h0 = xn;      // xn dead after G2/G3/conv
  short* h1 = xc;      // xc dead after G4
  short* hd = m2all;   // m2all dead after G5
  short* y2bf = ybf;   // ybf dead after expert first GEMMs
  float* y2   = ybuf;  // in-place rmsnorm

  auto cvt = [&](const float* s, short* d, int rows, int cols, int ld, int o){
    int n = rows*cols;
    int blocks = (n + 255)/256; if (blocks > 4096) blocks = 4096;
    cvt_submat<<<blocks, 256, 0, stream>>>(s, d, rows, cols, ld, o);
  };
  cvt(pw,   W_pw,             1024, 1024, 1024, 0);
  cvt(Wf_w, W_fxuwin,          256, 1024, 1280, 0);
  cvt(Wu_w, W_fxuwin+256*1024, 256, 1024, 1280, 0);
  cvt(Win_w,W_fxuwin+512*1024, 256, 1024, 1024, 0);
  cvt(Wo_w, W_ox,             1024, 1024, 1280, 0);
  cvt(Wf_w, W_fum,             256,  256, 1280, 1024);
  cvt(Wu_w, W_fum+256*256,     256,  256, 1280, 1024);
  cvt(Wo_w, W_om,             1024,  256, 1280, 1024);
  cvt(e0w1, W_e0w1,           1024, 1024, 1024, 0);
  cvt(e0w2, W_e0w2,           1024, 1024, 1024, 0);
  cvt(e1w1, W_e1w1,           1024, 1024, 1024, 0);
  cvt(e1w2, W_e1w2,           1024, 1024, 1024, 0);
  cvt(dnw,  W_down,            256, 1024, 1024, 0);
  cvt(upw,  W_up,             1024,  256,  256, 0);
  concat3<<<3, 256, 0, stream>>>(Wf_b, 256, Wu_b, 256, Win_b, 256, bias768);

  rmsnorm_k<<<NROWS, 256, 0, stream>>>(x, normw, xn);
  dwconv_k<<<(NROWS*DD)/256, 256, 0, stream>>>(xn, dwk, dwb, xc);

  // G2: fxu = xn @ [Wf_x;Wu_x;Win]^T + [Wf_b;Wu_b;Win_b]   (f32)
  gemm_bt<0,0,0><<<64*6, 256, 0, stream>>>(xn, W_fxuwin, bias768, nullptr, nullptr,
                                           fxu, NROWS, 768, 1024, 6);
  // G3: ybuf = xn @ Wo_x^T + Wo_b + x
  gemm_bt<0,0,0><<<64*8, 256, 0, stream>>>(xn, W_ox, Wo_b, x, nullptr,
                                           ybuf, NROWS, 1024, 1024, 8);
  // G4: ybuf += xc @ pw^T + pw_bias
  gemm_bt<0,1,0><<<64*8, 256, 0, stream>>>(xc, W_pw, pwb, nullptr, nullptr,
                                           ybuf, NROWS, 1024, 1024, 8);
  // sequential scan (writes m2all and new_mem)
  scan_k<<<1, 512, 0, stream>>>(fxu, W_fum, mem0, m2all,
                                (float*)d_out + (size_t)NROWS*DD);
  // G5: ybuf += m2 @ Wo_m^T   (rows of m2all are t*4+b -> permute to b*L+t)
  gemm_bt<0,1,1><<<64*8, 256, 0, stream>>>(m2all, W_om, nullptr, nullptr, nullptr,
                                           ybuf, NROWS, 1024, 256, 8);
  // ybf = bf16(y)
  f2b_k<<<(NROWS*DD/4 + 255)/256, 256, 0, stream>>>(ybuf, ybf, NROWS*DD/4);
  // experts
  gemm_bt<1,2,0><<<64*8, 256, 0, stream>>>(ybf, W_e0w1, e0b1, nullptr, nullptr,
                                           h0, NROWS, 1024, 1024, 8);
  gemm_bt<1,2,0><<<64*8, 256, 0, stream>>>(ybf, W_e1w1, e1b1, nullptr, nullptr,
                                           h1, NROWS, 1024, 1024, 8);
  gemm_bt<0,2,0><<<64*8, 256, 0, stream>>>(h0, W_e0w2, e0b2, nullptr, nullptr,
                                           e0v, NROWS, 1024, 1024, 8);
  gemm_bt<0,2,0><<<64*8, 256, 0, stream>>>(h1, W_e1w2, e1b2, nullptr, nullptr,
                                           e1v, NROWS, 1024, 1024, 8);
  // router softmax + expert mix + final rmsnorm (in-place into ybuf / y2bf)
  combine_k<<<NROWS, 256, 0, stream>>>(ybuf, e0v, e1v, rw, rb, fnw, y2bf);
  // G10: hd = gelu(y2 @ down^T + down_b)   (bf16)
  gemm_bt<2,2,0><<<64*2, 256, 0, stream>>>(y2bf, W_down, dnb, nullptr, nullptr,
                                           hd, NROWS, 256, 1024, 2);
  // G11: out = hd @ up^T + up_b + y2 + resid(x)
  gemm_bt<0,0,0><<<64*8, 256, 0, stream>>>(hd, W_up, upb, y2, (const float*)x,
                                           (float*)d_out, NROWS, 1024, 256, 8);
}

// Round 2
// 2466.439 us; speedup vs baseline: 1.3006x; 1.3006x over previous
//
#include <hip/hip_runtime.h>
#include <hip/hip_bf16.h>

#define DD 1024
#define MDD 256
#define LL 2048
#define BB 4
#define NROWS (BB*LL)   // 8192

typedef short bf16x8 __attribute__((ext_vector_type(8)));
typedef float f32x4 __attribute__((ext_vector_type(4)));

__device__ __forceinline__ short f2b(float x){
  __hip_bfloat16 h = __float2bfloat16(x);
  return *reinterpret_cast<short*>(&h);
}
__device__ __forceinline__ float b2f(short s){
  return __uint_as_float(((unsigned)(unsigned short)s) << 16);
}
__device__ __forceinline__ float frcp(float x){
#if __has_builtin(__builtin_amdgcn_rcpf)
  return __builtin_amdgcn_rcpf(x);
#else
  float r; asm("v_rcp_f32 %0, %1" : "=v"(r) : "v"(x)); return r;
#endif
}
__device__ __forceinline__ float fsigmoid(float x){
  return frcp(1.f + __expf(-x));
}

// ---------------- weight conversion ----------------
__global__ void cvt_submat(const float* __restrict__ src, short* __restrict__ dst,
                           int rows, int cols, int src_ld, int src_off){
  int n = rows*cols;
  for (int i = blockIdx.x*blockDim.x + threadIdx.x; i < n; i += gridDim.x*blockDim.x){
    int r = i / cols, c = i - r*cols;
    dst[i] = f2b(src[(size_t)r*src_ld + src_off + c]);
  }
}

__global__ void concat3(const float* __restrict__ a, int na,
                        const float* __restrict__ b, int nb,
                        const float* __restrict__ c, int nc,
                        float* __restrict__ dst){
  int i = blockIdx.x*blockDim.x + threadIdx.x;
  if (i < na) dst[i] = a[i];
  else if (i < na+nb) dst[i] = b[i-na];
  else if (i < na+nb+nc) dst[i] = c[i-na-nb];
}

// ---------------- rmsnorm (f32 in -> bf16 out) ----------------
__global__ __launch_bounds__(256) void rmsnorm_k(const float* __restrict__ x,
                                                 const float* __restrict__ w,
                                                 short* __restrict__ xn){
  int row = blockIdx.x, tid = threadIdx.x;
  const float* xr = x + (size_t)row*DD;
  float4 v = *(const float4*)&xr[tid*4];
  float ss = v.x*v.x + v.y*v.y + v.z*v.z + v.w*v.w;
  __shared__ float red[256];
  red[tid] = ss; __syncthreads();
  for (int s = 128; s > 0; s >>= 1){ if (tid < s) red[tid] += red[tid+s]; __syncthreads(); }
  float scale = rsqrtf(red[0]/(float)DD + 1e-6f);
  const float* wr = w + tid*4;
  short4 o;
  o.x = f2b(v.x*wr[0]*scale); o.y = f2b(v.y*wr[1]*scale);
  o.z = f2b(v.z*wr[2]*scale); o.w = f2b(v.w*wr[3]*scale);
  *(short4*)&xn[(size_t)row*DD + tid*4] = o;
}

// ---------------- depthwise causal conv K=5 ----------------
__global__ __launch_bounds__(256) void dwconv_k(const short* __restrict__ xn,
                                                const float* __restrict__ dwk,
                                                const float* __restrict__ dwb,
                                                short* __restrict__ xc){
  size_t i = (size_t)blockIdx.x*256 + threadIdx.x;  // over NROWS*DD
  int d = (int)(i & (DD-1));
  int l = (int)((i >> 10) & (LL-1));
  int b = (int)(i >> 21);
  float acc = dwb[d];
  const float* kk = dwk + d*5;
  #pragma unroll
  for (int k = 0; k < 5; ++k){
    int ll = l + k - 4;
    if (ll >= 0) acc += b2f(xn[((size_t)(b*LL + ll) << 10) + d]) * kk[k];
  }
  xc[i] = f2b(acc);
}

// ---------------- generic bf16 MFMA GEMM: C = act(A @ Bw^T + bias) (+adds) ----------------
// A: (M,K) bf16 row-major; Bw: (N,K) bf16 row-major. Staging via global_load_lds (m97 pattern).
// OUTMODE: 0=f32 store, 1=f32 accumulate, 2=bf16 store. ACT: 0 none,1 silu,2 exact gelu.
template<int ACT, int OUTMODE, int PERMUTE>
__global__ __launch_bounds__(256) void gemm_bt(
    const short* __restrict__ A, const short* __restrict__ Bw,
    const float* __restrict__ bias, const float* __restrict__ add0,
    const float* __restrict__ add1, void* __restrict__ Cout,
    int M, int N, int K, int nbn){
  __shared__ __align__(16) short As[128*32];
  __shared__ __align__(16) short Bs[128*32];
  int bm = blockIdx.x / nbn, bn = blockIdx.x % nbn;
  int tid = threadIdx.x, lane = tid & 63, w = tid >> 6;
  int wm = (w >> 1)*64, wn = (w & 1)*64;
  const int r0 = lane & 15, kg = lane >> 4;

  f32x4 acc[4][4];
  #pragma unroll
  for (int i = 0; i < 4; ++i)
    #pragma unroll
    for (int j = 0; j < 4; ++j)
      #pragma unroll
      for (int r = 0; r < 4; ++r) acc[i][j][r] = 0.f;

  // staging geometry: chunk c in [0,512) of 16B; row=c>>2, seg=c&3; LDS linear [128][32]
  const int c0 = w*64 + lane;
  const int c1 = c0 + 256;
  const short* a0 = &A [(size_t)(bm*128 + (c0 >> 2))*K + (c0 & 3)*8];
  const short* a1 = &A [(size_t)(bm*128 + (c1 >> 2))*K + (c1 & 3)*8];
  const short* b0 = &Bw[(size_t)(bn*128 + (c0 >> 2))*K + (c0 & 3)*8];
  const short* b1 = &Bw[(size_t)(bn*128 + (c1 >> 2))*K + (c1 & 3)*8];

  for (int k0 = 0; k0 < K; k0 += 32){
    __builtin_amdgcn_global_load_lds((const __attribute__((address_space(1))) void*)(a0 + k0),
                                     (__attribute__((address_space(3))) void*)&As[w*512], 16, 0, 0);
    __builtin_amdgcn_global_load_lds((const __attribute__((address_space(1))) void*)(b0 + k0),
                                     (__attribute__((address_space(3))) void*)&Bs[w*512], 16, 0, 0);
    __builtin_amdgcn_global_load_lds((const __attribute__((address_space(1))) void*)(a1 + k0),
                                     (__attribute__((address_space(3))) void*)&As[2048 + w*512], 16, 0, 0);
    __builtin_amdgcn_global_load_lds((const __attribute__((address_space(1))) void*)(b1 + k0),
                                     (__attribute__((address_space(3))) void*)&Bs[2048 + w*512], 16, 0, 0);
    __syncthreads();
    bf16x8 av[4], bv[4];
    #pragma unroll
    for (int i = 0; i < 4; ++i) av[i] = *(const bf16x8*)&As[(wm + i*16 + r0)*32 + kg*8];
    #pragma unroll
    for (int j = 0; j < 4; ++j) bv[j] = *(const bf16x8*)&Bs[(wn + j*16 + r0)*32 + kg*8];
    #pragma unroll
    for (int i = 0; i < 4; ++i)
      #pragma unroll
      for (int j = 0; j < 4; ++j)
        acc[i][j] = __builtin_amdgcn_mfma_f32_16x16x32_bf16(av[i], bv[j], acc[i][j], 0, 0, 0);
    __syncthreads();
  }

  #pragma unroll
  for (int i = 0; i < 4; ++i){
    int grb = bm*128 + wm + i*16 + kg*4;
    #pragma unroll
    for (int j = 0; j < 4; ++j){
      int gc = bn*128 + wn + j*16 + r0;
      float bvv = bias ? bias[gc] : 0.f;
      #pragma unroll
      for (int r = 0; r < 4; ++r){
        int gr = grb + r;
        float v = acc[i][j][r] + bvv;
        if (ACT == 1) v = v / (1.f + __expf(-v));
        else if (ACT == 2) v = 0.5f*v*(1.f + erff(v*0.70710678118f));
        size_t orow = PERMUTE ? (size_t)((gr & 3)*LL + (gr >> 2)) : (size_t)gr;
        size_t oi = orow*(size_t)N + gc;
        if (add0) v += add0[oi];
        if (add1) v += add1[oi];
        if (OUTMODE == 0) ((float*)Cout)[oi] = v;
        else if (OUTMODE == 1) ((float*)Cout)[oi] += v;
        else ((short*)Cout)[oi] = f2b(v);
      }
    }
  }
}

// ---------------- f32 -> bf16 bulk convert ----------------
__global__ __launch_bounds__(256) void f2b_k(const float* __restrict__ src,
                                             short* __restrict__ dst, int n4){
  int i = blockIdx.x*256 + threadIdx.x;
  if (i < n4){
    float4 v = *(const float4*)&src[(size_t)i*4];
    short4 o; o.x = f2b(v.x); o.y = f2b(v.y); o.z = f2b(v.z); o.w = f2b(v.w);
    *(short4*)&dst[(size_t)i*4] = o;
  }
}

// ---------------- sequential recurrence (1 block, 8 waves, 1 raw barrier/step) ----------------
// fxu rows = b*LL + t, 768 cols: [0,256)=fx, [256,512)=ux, [512,768)=xm_raw.
// Wfu: (512,256) bf16 = [Wf_m ; Wu_m]. m2all rows = t*4+b (bf16).
// Wave w owns j-range [w*32, w*32+32). Lane (kg,r0): batch b=kg, cols j0=w*32+r0 and j0+16.
// m state: f32 in regs (per-lane), bf16 A-tile double-buffered in LDS.
__global__ __launch_bounds__(512) void scan_k(
    const float* __restrict__ fxu, const short* __restrict__ Wfu,
    const float* __restrict__ m0, short* __restrict__ m2all,
    float* __restrict__ newmem){
  __shared__ __align__(16) short mA[2][16*264];  // [buf][batch-row][k], rows 4..15 zero
  __shared__ float gbuf[8*256];                  // per-wave gate exchange [w][fuP][r][r0]
  const int tid = threadIdx.x, lane = tid & 63, w = tid >> 6;
  const int r0 = lane & 15, kg = lane >> 4;
  const int j0 = w*32 + r0;

  for (int i = tid; i < 2*16*264; i += 512) ((short*)mA)[i] = 0;

  // gate weights resident in VGPRs: bw[fu][p][kt], n-tile base = fu*256 + w*32 + p*16
  bf16x8 bw[2][2][8];
  #pragma unroll
  for (int fu = 0; fu < 2; ++fu)
    #pragma unroll
    for (int p = 0; p < 2; ++p)
      #pragma unroll
      for (int kt = 0; kt < 8; ++kt)
        bw[fu][p][kt] = *(const bf16x8*)&Wfu[(size_t)(fu*256 + w*32 + p*16 + r0)*256 + kt*32 + kg*8];

  float m_reg0 = m0[kg*256 + j0];
  float m_reg1 = m0[kg*256 + j0 + 16];

  // prefetch fxu for t=0
  float pf_f0, pf_f1, pf_u0, pf_u1, pf_x0, pf_x1;
  {
    size_t base = (size_t)kg*LL*768;
    pf_f0 = fxu[base + j0];        pf_f1 = fxu[base + j0 + 16];
    pf_u0 = fxu[base + 256 + j0];  pf_u1 = fxu[base + 256 + j0 + 16];
    pf_x0 = fxu[base + 512 + j0];  pf_x1 = fxu[base + 512 + j0 + 16];
  }
  __syncthreads();          // zeroing visible
  mA[0][kg*264 + j0]      = f2b(m_reg0);
  mA[0][kg*264 + j0 + 16] = f2b(m_reg1);
  __syncthreads();          // init visible

  for (int t = 0; t < LL; ++t){
    const short* mac = mA[t & 1];
    short*       man = mA[(t & 1) ^ 1];

    // A-fragments (full m, bf16)
    bf16x8 af[8];
    #pragma unroll
    for (int kt = 0; kt < 8; ++kt)
      af[kt] = *(const bf16x8*)&mac[r0*264 + kt*32 + kg*8];

    f32x4 aF0 = {0.f,0.f,0.f,0.f}, aF1 = {0.f,0.f,0.f,0.f};
    f32x4 aU0 = {0.f,0.f,0.f,0.f}, aU1 = {0.f,0.f,0.f,0.f};
    #pragma unroll
    for (int kt = 0; kt < 8; ++kt){
      aF0 = __builtin_amdgcn_mfma_f32_16x16x32_bf16(af[kt], bw[0][0][kt], aF0, 0, 0, 0);
      aF1 = __builtin_amdgcn_mfma_f32_16x16x32_bf16(af[kt], bw[0][1][kt], aF1, 0, 0, 0);
      aU0 = __builtin_amdgcn_mfma_f32_16x16x32_bf16(af[kt], bw[1][0][kt], aU0, 0, 0, 0);
      aU1 = __builtin_amdgcn_mfma_f32_16x16x32_bf16(af[kt], bw[1][1][kt], aU1, 0, 0, 0);
    }

    // same-wave gate exchange: kg==0 rows hold valid batches 0..3
    if (kg == 0){
      #pragma unroll
      for (int r = 0; r < 4; ++r){
        gbuf[w*256 +       r*16 + r0] = aF0[r];
        gbuf[w*256 +  64 + r*16 + r0] = aF1[r];
        gbuf[w*256 + 128 + r*16 + r0] = aU0[r];
        gbuf[w*256 + 192 + r*16 + r0] = aU1[r];
      }
    }
    __builtin_amdgcn_sched_barrier(0);   // keep reads after writes (same-wave LDS is in-order)
    float gF0 = gbuf[w*256 +       kg*16 + r0];
    float gF1 = gbuf[w*256 +  64 + kg*16 + r0];
    float gU0 = gbuf[w*256 + 128 + kg*16 + r0];
    float gU1 = gbuf[w*256 + 192 + kg*16 + r0];

    float f0 = fsigmoid(gF0 + pf_f0);
    float f1 = fsigmoid(gF1 + pf_f1);
    float u0 = fsigmoid(gU0 + pf_u0);
    float u1 = fsigmoid(gU1 + pf_u1);
    float xm0 = pf_x0 * fsigmoid(pf_x0);
    float xm1 = pf_x1 * fsigmoid(pf_x1);
    m_reg0 = f0*m_reg0 + u0*xm0;
    m_reg1 = f1*m_reg1 + u1*xm1;
    short mb0 = f2b(m_reg0), mb1 = f2b(m_reg1);

    // stream out m_t (stores stay in flight across raw barrier)
    m2all[(size_t)(t*4 + kg)*256 + j0]      = mb0;
    m2all[(size_t)(t*4 + kg)*256 + j0 + 16] = mb1;

    // prefetch fxu for t+1 (consumed next iter; ~1 step of latency hiding)
    int t1 = (t + 1 < LL) ? t + 1 : t;
    size_t base = ((size_t)kg*LL + t1)*768;
    pf_f0 = fxu[base + j0];        pf_f1 = fxu[base + j0 + 16];
    pf_u0 = fxu[base + 256 + j0];  pf_u1 = fxu[base + 256 + j0 + 16];
    pf_x0 = fxu[base + 512 + j0];  pf_x1 = fxu[base + 512 + j0 + 16];

    // publish m_t into the other buffer; only LDS must drain before barrier
    man[kg*264 + j0]      = mb0;
    man[kg*264 + j0 + 16] = mb1;
    asm volatile("s_waitcnt lgkmcnt(0)" ::: "memory");
    __builtin_amdgcn_sched_barrier(0);
    __builtin_amdgcn_s_barrier();
    __builtin_amdgcn_sched_barrier(0);
  }

  newmem[kg*256 + j0]      = m_reg0;
  newmem[kg*256 + j0 + 16] = m_reg1;
}

// ---------------- router + expert combine + final rmsnorm ----------------
__global__ __launch_bounds__(256) void combine_k(
    float* __restrict__ y, const short* __restrict__ e0, const short* __restrict__ e1,
    const float* __restrict__ rw, const float* __restrict__ rb,
    const float* __restrict__ fw, short* __restrict__ y2bf){
  int row = blockIdx.x, tid = threadIdx.x;
  size_t base = (size_t)row*DD + tid*4;
  float4 vy = *(const float4*)&y[base];
  short4 s0 = *(const short4*)&e0[base];
  short4 s1 = *(const short4*)&e1[base];
  float4 w0 = *(const float4*)&rw[tid*4];
  float4 w1 = *(const float4*)&rw[DD + tid*4];
  float d0 = vy.x*w0.x + vy.y*w0.y + vy.z*w0.z + vy.w*w0.w;
  float d1 = vy.x*w1.x + vy.y*w1.y + vy.z*w1.z + vy.w*w1.w;
  __shared__ float redA[256], redB[256];
  redA[tid] = d0; redB[tid] = d1; __syncthreads();
  for (int s = 128; s > 0; s >>= 1){
    if (tid < s){ redA[tid] += redA[tid+s]; redB[tid] += redB[tid+s]; }
    __syncthreads();
  }
  float l0 = redA[0] + rb[0], l1 = redB[0] + rb[1];
  float p0 = 1.f/(1.f + __expf(l1 - l0));
  float p1 = 1.f - p0;
  float c0 = vy.x + p0*b2f(s0.x) + p1*b2f(s1.x);
  float c1 = vy.y + p0*b2f(s0.y) + p1*b2f(s1.y);
  float c2 = vy.z + p0*b2f(s0.z) + p1*b2f(s1.z);
  float c3 = vy.w + p0*b2f(s0.w) + p1*b2f(s1.w);
  float ss = c0*c0 + c1*c1 + c2*c2 + c3*c3;
  __syncthreads();
  redA[tid] = ss; __syncthreads();
  for (int s = 128; s > 0; s >>= 1){
    if (tid < s) redA[tid] += redA[tid+s];
    __syncthreads();
  }
  float scale = rsqrtf(redA[0]/(float)DD + 1e-6f);
  const float* fwp = fw + tid*4;
  float o0 = c0*fwp[0]*scale, o1 = c1*fwp[1]*scale, o2 = c2*fwp[2]*scale, o3 = c3*fwp[3]*scale;
  float4 ov; ov.x = o0; ov.y = o1; ov.z = o2; ov.w = o3;
  *(float4*)&y[base] = ov;
  short4 ob; ob.x = f2b(o0); ob.y = f2b(o1); ob.z = f2b(o2); ob.w = f2b(o3);
  *(short4*)&y2bf[base] = ob;
}

// ---------------- host ----------------
extern "C" void kernel_launch(void* const* d_in, const int* in_sizes, int n_in,
                              void* d_out, int out_size, void* d_ws, size_t ws_size,
                              hipStream_t stream){
  (void)in_sizes; (void)n_in; (void)out_size; (void)ws_size;
  const float* x     = (const float*)d_in[0];
  const float* mem0  = (const float*)d_in[1];
  const float* normw = (const float*)d_in[2];
  const float* dwk   = (const float*)d_in[3];
  const float* dwb   = (const float*)d_in[4];
  const float* pw    = (const float*)d_in[5];
  const float* pwb   = (const float*)d_in[6];
  const float* Win_w = (const float*)d_in[7];
  const float* Win_b = (const float*)d_in[8];
  const float* Wf_w  = (const float*)d_in[9];
  const float* Wf_b  = (const float*)d_in[10];
  const float* Wu_w  = (const float*)d_in[11];
  const float* Wu_b  = (const float*)d_in[12];
  const float* Wo_w  = (const float*)d_in[13];
  const float* Wo_b  = (const float*)d_in[14];
  const float* rw    = (const float*)d_in[15];
  const float* rb    = (const float*)d_in[16];
  const float* e0w1  = (const float*)d_in[17];
  const float* e0b1  = (const float*)d_in[18];
  const float* e0w2  = (const float*)d_in[19];
  const float* e0b2  = (const float*)d_in[20];
  const float* e1w1  = (const float*)d_in[21];
  const float* e1b1  = (const float*)d_in[22];
  const float* e1w2  = (const float*)d_in[23];
  const float* e1b2  = (const float*)d_in[24];
  const float* fnw   = (const float*)d_in[25];
  const float* dnw   = (const float*)d_in[26];
  const float* dnb   = (const float*)d_in[27];
  const float* upw   = (const float*)d_in[28];
  const float* upb   = (const float*)d_in[29];

  char* ws = (char*)d_ws;
  size_t off = 0;
  auto alloc = [&](size_t bytes)->char*{
    char* p = ws + off; off += (bytes + 255) & ~(size_t)255; return p;
  };
  short* W_pw     = (short*)alloc((size_t)1024*1024*2);
  short* W_fxuwin = (short*)alloc((size_t)768*1024*2);
  short* W_ox     = (short*)alloc((size_t)1024*1024*2);
  short* W_fum    = (short*)alloc((size_t)512*256*2);
  short* W_om     = (short*)alloc((size_t)1024*256*2);
  short* W_e0w1   = (short*)alloc((size_t)1024*1024*2);
  short* W_e0w2   = (short*)alloc((size_t)1024*1024*2);
  short* W_e1w1   = (short*)alloc((size_t)1024*1024*2);
  short* W_e1w2   = (short*)alloc((size_t)1024*1024*2);
  short* W_down   = (short*)alloc((size_t)256*1024*2);
  short* W_up     = (short*)alloc((size_t)1024*256*2);
  float* bias768  = (float*)alloc(768*4);
  short* xn       = (short*)alloc((size_t)NROWS*DD*2);
  short* xc       = (short*)alloc((size_t)NROWS*DD*2);
  float* fxu      = (float*)alloc((size_t)NROWS*768*4);
  float* ybuf     = (float*)alloc((size_t)NROWS*DD*4);
  short* m2all    = (short*)alloc((size_t)NROWS*MDD*2);
  short* ybf      = (short*)alloc((size_t)NROWS*DD*2);
  short* e0v      = (short*)alloc((size_t)NROWS*DD*2);
  short* e1v      = (short*)alloc((size_t)NROWS*DD*2);
  short* h0 = xn;      // xn dead after G2/G3/conv
  short* h1 = xc;      // xc dead after G4
  short* hd = m2all;   // m2all dead after G5
  short* y2bf = ybf;   // ybf dead after expert first GEMMs
  float* y2   = ybuf;  // in-place rmsnorm

  auto cvt = [&](const float* s, short* d, int rows, int cols, int ld, int o){
    int n = rows*cols;
    int blocks = (n + 255)/256; if (blocks > 4096) blocks = 4096;
    cvt_submat<<<blocks, 256, 0, stream>>>(s, d, rows, cols, ld, o);
  };
  cvt(pw,   W_pw,             1024, 1024, 1024, 0);
  cvt(Wf_w, W_fxuwin,          256, 1024, 1280, 0);
  cvt(Wu_w, W_fxuwin+256*1024, 256, 1024, 1280, 0);
  cvt(Win_w,W_fxuwin+512*1024, 256, 1024, 1024, 0);
  cvt(Wo_w, W_ox,             1024, 1024, 1280, 0);
  cvt(Wf_w, W_fum,             256,  256, 1280, 1024);
  cvt(Wu_w, W_fum+256*256,     256,  256, 1280, 1024);
  cvt(Wo_w, W_om,             1024,  256, 1280, 1024);
  cvt(e0w1, W_e0w1,           1024, 1024, 1024, 0);
  cvt(e0w2, W_e0w2,           1024, 1024, 1024, 0);
  cvt(e1w1, W_e1w1,           1024, 1024, 1024, 0);
  cvt(e1w2, W_e1w2,           1024, 1024, 1024, 0);
  cvt(dnw,  W_down,            256, 1024, 1024, 0);
  cvt(upw,  W_up,             1024,  256,  256, 0);
  concat3<<<3, 256, 0, stream>>>(Wf_b, 256, Wu_b, 256, Win_b, 256, bias768);

  rmsnorm_k<<<NROWS, 256, 0, stream>>>(x, normw, xn);
  dwconv_k<<<(NROWS*DD)/256, 256, 0, stream>>>(xn, dwk, dwb, xc);

  // G2: fxu = xn @ [Wf_x;Wu_x;Win]^T + [Wf_b;Wu_b;Win_b]   (f32)
  gemm_bt<0,0,0><<<64*6, 256, 0, stream>>>(xn, W_fxuwin, bias768, nullptr, nullptr,
                                           fxu, NROWS, 768, 1024, 6);
  // G3: ybuf = xn @ Wo_x^T + Wo_b + x
  gemm_bt<0,0,0><<<64*8, 256, 0, stream>>>(xn, W_ox, Wo_b, x, nullptr,
                                           ybuf, NROWS, 1024, 1024, 8);
  // G4: ybuf += xc @ pw^T + pw_bias
  gemm_bt<0,1,0><<<64*8, 256, 0, stream>>>(xc, W_pw, pwb, nullptr, nullptr,
                                           ybuf, NROWS, 1024, 1024, 8);
  // sequential scan (writes m2all and new_mem)
  scan_k<<<1, 512, 0, stream>>>(fxu, W_fum, mem0, m2all,
                                (float*)d_out + (size_t)NROWS*DD);
  // G5: ybuf += m2 @ Wo_m^T   (rows of m2all are t*4+b -> permute to b*L+t)
  gemm_bt<0,1,1><<<64*8, 256, 0, stream>>>(m2all, W_om, nullptr, nullptr, nullptr,
                                           ybuf, NROWS, 1024, 256, 8);
  // ybf = bf16(y)
  f2b_k<<<(NROWS*DD/4 + 255)/256, 256, 0, stream>>>(ybuf, ybf, NROWS*DD/4);
  // experts
  gemm_bt<1,2,0><<<64*8, 256, 0, stream>>>(ybf, W_e0w1, e0b1, nullptr, nullptr,
                                           h0, NROWS, 1024, 1024, 8);
  gemm_bt<1,2,0><<<64*8, 256, 0, stream>>>(ybf, W_e1w1, e1b1, nullptr, nullptr,
                                           h1, NROWS, 1024, 1024, 8);
  gemm_bt<0,2,0><<<64*8, 256, 0, stream>>>(h0, W_e0w2, e0b2, nullptr, nullptr,
                                           e0v, NROWS, 1024, 1024, 8);
  gemm_bt<0,2,0><<<64*8, 256, 0, stream>>>(h1, W_e1w2, e1b2, nullptr, nullptr,
                                           e1v, NROWS, 1024, 1024, 8);
  // router softmax + expert mix + final rmsnorm (in-place into ybuf / y2bf)
  combine_k<<<NROWS, 256, 0, stream>>>(ybuf, e0v, e1v, rw, rb, fnw, y2bf);
  // G10: hd = gelu(y2 @ down^T + down_b)   (bf16)
  gemm_bt<2,2,0><<<64*2, 256, 0, stream>>>(y2bf, W_down, dnb, nullptr, nullptr,
                                           hd, NROWS, 256, 1024, 2);
  // G11: out = hd @ up^T + up_b + y2 + resid(x)
  gemm_bt<0,0,0><<<64*8, 256, 0, stream>>>(hd, W_up, upb, y2, (const float*)x,
                                           (float*)d_out, NROWS, 1024, 256, 8);
}

// Round 3
// 2095.392 us; speedup vs baseline: 1.5309x; 1.1771x over previous
//
#include <hip/hip_runtime.h>
#include <hip/hip_bf16.h>

#define DD 1024
#define MDD 256
#define LL 2048
#define BB 4
#define NROWS (BB*LL)   // 8192

typedef short bf16x8 __attribute__((ext_vector_type(8)));
typedef float f32x4 __attribute__((ext_vector_type(4)));

__device__ __forceinline__ short f2b(float x){
  __hip_bfloat16 h = __float2bfloat16(x);
  return *reinterpret_cast<short*>(&h);
}
__device__ __forceinline__ float b2f(short s){
  return __uint_as_float(((unsigned)(unsigned short)s) << 16);
}
__device__ __forceinline__ float frcp(float x){
#if __has_builtin(__builtin_amdgcn_rcpf)
  return __builtin_amdgcn_rcpf(x);
#else
  float r; asm("v_rcp_f32 %0, %1" : "=v"(r) : "v"(x)); return r;
#endif
}
__device__ __forceinline__ float fsigmoid(float x){
  return frcp(1.f + __expf(-x));
}
// select a[kg] without dynamic vector indexing (rule #20): 3 cndmask
__device__ __forceinline__ float sel4(f32x4 a, int kg){
  float lo = (kg & 1) ? a[1] : a[0];
  float hi = (kg & 1) ? a[3] : a[2];
  return (kg & 2) ? hi : lo;
}

// ---------------- weight conversion (strided dst) ----------------
__global__ void cvt_submat(const float* __restrict__ src, short* __restrict__ dst,
                           int rows, int cols, int src_ld, int src_off, int dst_ld){
  int n = rows*cols;
  for (int i = blockIdx.x*blockDim.x + threadIdx.x; i < n; i += gridDim.x*blockDim.x){
    int r = i / cols, c = i - r*cols;
    dst[(size_t)r*dst_ld + c] = f2b(src[(size_t)r*src_ld + src_off + c]);
  }
}

__global__ void concat3(const float* __restrict__ a, int na,
                        const float* __restrict__ b, int nb,
                        const float* __restrict__ c, int nc,
                        float* __restrict__ dst){
  int i = blockIdx.x*blockDim.x + threadIdx.x;
  if (i < na) dst[i] = a[i];
  else if (i < na+nb) dst[i] = b[i-na];
  else if (i < na+nb+nc) dst[i] = c[i-na-nb];
}

__global__ void addvec_k(const float* __restrict__ a, const float* __restrict__ b,
                         float* __restrict__ dst, int n){
  int i = blockIdx.x*blockDim.x + threadIdx.x;
  if (i < n) dst[i] = a[i] + b[i];
}

// ---------------- rmsnorm (f32 in -> bf16 out, strided out) ----------------
__global__ __launch_bounds__(256) void rmsnorm_k(const float* __restrict__ x,
                                                 const float* __restrict__ w,
                                                 short* __restrict__ xn){
  int row = blockIdx.x, tid = threadIdx.x;
  const float* xr = x + (size_t)row*DD;
  float4 v = *(const float4*)&xr[tid*4];
  float ss = v.x*v.x + v.y*v.y + v.z*v.z + v.w*v.w;
  __shared__ float red[256];
  red[tid] = ss; __syncthreads();
  for (int s = 128; s > 0; s >>= 1){ if (tid < s) red[tid] += red[tid+s]; __syncthreads(); }
  float scale = rsqrtf(red[0]/(float)DD + 1e-6f);
  const float* wr = w + tid*4;
  short4 o;
  o.x = f2b(v.x*wr[0]*scale); o.y = f2b(v.y*wr[1]*scale);
  o.z = f2b(v.z*wr[2]*scale); o.w = f2b(v.w*wr[3]*scale);
  *(short4*)&xn[(size_t)row*2048 + tid*4] = o;
}

// ---------------- depthwise causal conv K=5 (strided in/out: A2 layout) ----------------
__global__ __launch_bounds__(256) void dwconv_k(const short* __restrict__ xnA,
                                                const float* __restrict__ dwk,
                                                const float* __restrict__ dwb,
                                                short* __restrict__ xcA){
  size_t i = (size_t)blockIdx.x*256 + threadIdx.x;  // over NROWS*DD
  int d = (int)(i & (DD-1));
  int l = (int)((i >> 10) & (LL-1));
  int b = (int)(i >> 21);
  float acc = dwb[d];
  const float* kk = dwk + d*5;
  #pragma unroll
  for (int k = 0; k < 5; ++k){
    int ll = l + k - 4;
    if (ll >= 0) acc += b2f(xnA[((size_t)(b*LL + ll))*2048 + d]) * kk[k];
  }
  xcA[((size_t)(b*LL + l))*2048 + 1024 + d] = f2b(acc);
}

// ---------------- generic bf16 MFMA GEMM: C = act(A @ Bw^T + bias) (+adds) ----------------
// A: (M,K) bf16 rows stride lda; Bw: (N,K) bf16 rows stride K (contig).
// OUTMODE: 0=f32 store, 1=f32 accumulate, 2=bf16 store, 3=f32 accumulate + bf16 2nd out.
// ACT: 0 none, 1 silu, 2 exact gelu.
template<int ACT, int OUTMODE, int PERMUTE>
__global__ __launch_bounds__(256) void gemm_bt(
    const short* __restrict__ A, const short* __restrict__ Bw,
    const float* __restrict__ bias, const float* __restrict__ add0,
    void* __restrict__ Cout, short* __restrict__ Cout2,
    int M, int N, int K, int lda, int nbn){
  __shared__ __align__(16) short As[128*32];
  __shared__ __align__(16) short Bs[128*32];
  int bm = blockIdx.x / nbn, bn = blockIdx.x % nbn;
  int tid = threadIdx.x, lane = tid & 63, w = tid >> 6;
  int wm = (w >> 1)*64, wn = (w & 1)*64;
  const int r0 = lane & 15, kg = lane >> 4;

  f32x4 acc[4][4];
  #pragma unroll
  for (int i = 0; i < 4; ++i)
    #pragma unroll
    for (int j = 0; j < 4; ++j)
      #pragma unroll
      for (int r = 0; r < 4; ++r) acc[i][j][r] = 0.f;

  // staging geometry: chunk c in [0,512) of 16B; row=c>>2, seg=c&3; LDS linear [128][32]
  const int c0 = w*64 + lane;
  const int c1 = c0 + 256;
  const short* a0 = &A [(size_t)(bm*128 + (c0 >> 2))*lda + (c0 & 3)*8];
  const short* a1 = &A [(size_t)(bm*128 + (c1 >> 2))*lda + (c1 & 3)*8];
  const short* b0 = &Bw[(size_t)(bn*128 + (c0 >> 2))*K + (c0 & 3)*8];
  const short* b1 = &Bw[(size_t)(bn*128 + (c1 >> 2))*K + (c1 & 3)*8];

  for (int k0 = 0; k0 < K; k0 += 32){
    __builtin_amdgcn_global_load_lds((const __attribute__((address_space(1))) void*)(a0 + k0),
                                     (__attribute__((address_space(3))) void*)&As[w*512], 16, 0, 0);
    __builtin_amdgcn_global_load_lds((const __attribute__((address_space(1))) void*)(b0 + k0),
                                     (__attribute__((address_space(3))) void*)&Bs[w*512], 16, 0, 0);
    __builtin_amdgcn_global_load_lds((const __attribute__((address_space(1))) void*)(a1 + k0),
                                     (__attribute__((address_space(3))) void*)&As[2048 + w*512], 16, 0, 0);
    __builtin_amdgcn_global_load_lds((const __attribute__((address_space(1))) void*)(b1 + k0),
                                     (__attribute__((address_space(3))) void*)&Bs[2048 + w*512], 16, 0, 0);
    __syncthreads();
    bf16x8 av[4], bv[4];
    #pragma unroll
    for (int i = 0; i < 4; ++i) av[i] = *(const bf16x8*)&As[(wm + i*16 + r0)*32 + kg*8];
    #pragma unroll
    for (int j = 0; j < 4; ++j) bv[j] = *(const bf16x8*)&Bs[(wn + j*16 + r0)*32 + kg*8];
    #pragma unroll
    for (int i = 0; i < 4; ++i)
      #pragma unroll
      for (int j = 0; j < 4; ++j)
        acc[i][j] = __builtin_amdgcn_mfma_f32_16x16x32_bf16(av[i], bv[j], acc[i][j], 0, 0, 0);
    __syncthreads();
  }

  #pragma unroll
  for (int i = 0; i < 4; ++i){
    int grb = bm*128 + wm + i*16 + kg*4;
    #pragma unroll
    for (int j = 0; j < 4; ++j){
      int gc = bn*128 + wn + j*16 + r0;
      float bvv = bias ? bias[gc] : 0.f;
      #pragma unroll
      for (int r = 0; r < 4; ++r){
        int gr = grb + r;
        float v = acc[i][j][r] + bvv;
        if (ACT == 1) v = v / (1.f + __expf(-v));
        else if (ACT == 2) v = 0.5f*v*(1.f + erff(v*0.70710678118f));
        size_t orow = PERMUTE ? (size_t)((gr & 3)*LL + (gr >> 2)) : (size_t)gr;
        size_t oi = orow*(size_t)N + gc;
        if (add0) v += add0[oi];
        if (OUTMODE == 0) ((float*)Cout)[oi] = v;
        else if (OUTMODE == 1) ((float*)Cout)[oi] += v;
        else if (OUTMODE == 2) ((short*)Cout)[oi] = f2b(v);
        else {
          float nv = ((float*)Cout)[oi] + v;
          ((float*)Cout)[oi] = nv;
          Cout2[oi] = f2b(nv);
        }
      }
    }
  }
}

// ---------------- sequential recurrence (1 block, 8 waves, 1 raw barrier/step) ----------------
// fxu rows = b*LL + t, 768 cols: [0,256)=fx, [256,512)=ux, [512,768)=xm_raw.
// Wfu: (512,256) bf16 = [Wf_m ; Wu_m]. m2all rows = t*4+b (bf16).
// Wave w owns j-range [w*32, w*32+32). Lane (kg,r0): batch kg, cols j0=w*32+r0, j0+16.
// A-rows are batch-duplicated (row r = batch r&3) so every lane gets all 4 batches of its
// own output column in its accumulator registers -> gate select is 3 cndmask, no LDS trip.
__global__ __launch_bounds__(512) void scan_k(
    const float* __restrict__ fxu, const short* __restrict__ Wfu,
    const float* __restrict__ m0, short* __restrict__ m2all,
    float* __restrict__ newmem){
  __shared__ __align__(16) short mA[2][4*272];   // [buf][batch][k], row stride 272
  const int tid = threadIdx.x, lane = tid & 63, w = tid >> 6;
  const int r0 = lane & 15, kg = lane >> 4;
  const int j0 = w*32 + r0;

  // gate weights resident in VGPRs: bw[fu][p][kt], n-tile base = fu*256 + w*32 + p*16
  bf16x8 bw[2][2][8];
  #pragma unroll
  for (int fu = 0; fu < 2; ++fu)
    #pragma unroll
    for (int p = 0; p < 2; ++p)
      #pragma unroll
      for (int kt = 0; kt < 8; ++kt)
        bw[fu][p][kt] = *(const bf16x8*)&Wfu[(size_t)(fu*256 + w*32 + p*16 + r0)*256 + kt*32 + kg*8];

  float m_reg0 = m0[kg*256 + j0];
  float m_reg1 = m0[kg*256 + j0 + 16];

  // prefetch fxu for t=0
  float pf_f0, pf_f1, pf_u0, pf_u1, pf_x0, pf_x1;
  {
    size_t base = (size_t)kg*LL*768;
    pf_f0 = fxu[base + j0];        pf_f1 = fxu[base + j0 + 16];
    pf_u0 = fxu[base + 256 + j0];  pf_u1 = fxu[base + 256 + j0 + 16];
    pf_x0 = fxu[base + 512 + j0];  pf_x1 = fxu[base + 512 + j0 + 16];
  }
  mA[0][kg*272 + j0]      = f2b(m_reg0);
  mA[0][kg*272 + j0 + 16] = f2b(m_reg1);
  __syncthreads();

  for (int t = 0; t < LL; ++t){
    const short* mac = mA[t & 1];
    short*       man = mA[(t & 1) ^ 1];

    // A-fragments: row = batch (r0&3) -> 4-lane broadcast reads, conflict-lite
    bf16x8 af[8];
    #pragma unroll
    for (int kt = 0; kt < 8; ++kt)
      af[kt] = *(const bf16x8*)&mac[(r0 & 3)*272 + kt*32 + kg*8];

    f32x4 aF0 = {0.f,0.f,0.f,0.f}, aF1 = {0.f,0.f,0.f,0.f};
    f32x4 aU0 = {0.f,0.f,0.f,0.f}, aU1 = {0.f,0.f,0.f,0.f};
    #pragma unroll
    for (int kt = 0; kt < 8; ++kt){
      aF0 = __builtin_amdgcn_mfma_f32_16x16x32_bf16(af[kt], bw[0][0][kt], aF0, 0, 0, 0);
      aF1 = __builtin_amdgcn_mfma_f32_16x16x32_bf16(af[kt], bw[0][1][kt], aF1, 0, 0, 0);
      aU0 = __builtin_amdgcn_mfma_f32_16x16x32_bf16(af[kt], bw[1][0][kt], aU0, 0, 0, 0);
      aU1 = __builtin_amdgcn_mfma_f32_16x16x32_bf16(af[kt], bw[1][1][kt], aU1, 0, 0, 0);
    }

    // acc reg r holds batch r (rows duplicated mod 4) -> in-register gate select
    float gF0 = sel4(aF0, kg), gF1 = sel4(aF1, kg);
    float gU0 = sel4(aU0, kg), gU1 = sel4(aU1, kg);

    float f0 = fsigmoid(gF0 + pf_f0);
    float f1 = fsigmoid(gF1 + pf_f1);
    float u0 = fsigmoid(gU0 + pf_u0);
    float u1 = fsigmoid(gU1 + pf_u1);
    float xm0 = pf_x0 * fsigmoid(pf_x0);
    float xm1 = pf_x1 * fsigmoid(pf_x1);
    m_reg0 = f0*m_reg0 + u0*xm0;
    m_reg1 = f1*m_reg1 + u1*xm1;
    short mb0 = f2b(m_reg0), mb1 = f2b(m_reg1);

    // stream out m_t (global stores stay in flight across the raw barrier)
    m2all[(size_t)(t*4 + kg)*256 + j0]      = mb0;
    m2all[(size_t)(t*4 + kg)*256 + j0 + 16] = mb1;

    // prefetch fxu for t+1
    int t1 = (t + 1 < LL) ? t + 1 : t;
    size_t base = ((size_t)kg*LL + t1)*768;
    pf_f0 = fxu[base + j0];        pf_f1 = fxu[base + j0 + 16];
    pf_u0 = fxu[base + 256 + j0];  pf_u1 = fxu[base + 256 + j0 + 16];
    pf_x0 = fxu[base + 512 + j0];  pf_x1 = fxu[base + 512 + j0 + 16];

    // publish m_t into the other buffer; only LDS must drain before barrier
    man[kg*272 + j0]      = mb0;
    man[kg*272 + j0 + 16] = mb1;
    asm volatile("s_waitcnt lgkmcnt(0)" ::: "memory");
    __builtin_amdgcn_sched_barrier(0);
    __builtin_amdgcn_s_barrier();
    __builtin_amdgcn_sched_barrier(0);
  }

  newmem[kg*256 + j0]      = m_reg0;
  newmem[kg*256 + j0 + 16] = m_reg1;
}

// ---------------- router + expert combine + final rmsnorm ----------------
__global__ __launch_bounds__(256) void combine_k(
    float* __restrict__ y, const short* __restrict__ e0, const short* __restrict__ e1,
    const float* __restrict__ rw, const float* __restrict__ rb,
    const float* __restrict__ fw, short* __restrict__ y2bf){
  int row = blockIdx.x, tid = threadIdx.x;
  size_t base = (size_t)row*DD + tid*4;
  float4 vy = *(const float4*)&y[base];
  short4 s0 = *(const short4*)&e0[base];
  short4 s1 = *(const short4*)&e1[base];
  float4 w0 = *(const float4*)&rw[tid*4];
  float4 w1 = *(const float4*)&rw[DD + tid*4];
  float d0 = vy.x*w0.x + vy.y*w0.y + vy.z*w0.z + vy.w*w0.w;
  float d1 = vy.x*w1.x + vy.y*w1.y + vy.z*w1.z + vy.w*w1.w;
  __shared__ float redA[256], redB[256];
  redA[tid] = d0; redB[tid] = d1; __syncthreads();
  for (int s = 128; s > 0; s >>= 1){
    if (tid < s){ redA[tid] += redA[tid+s]; redB[tid] += redB[tid+s]; }
    __syncthreads();
  }
  float l0 = redA[0] + rb[0], l1 = redB[0] + rb[1];
  float p0 = 1.f/(1.f + __expf(l1 - l0));
  float p1 = 1.f - p0;
  float c0 = vy.x + p0*b2f(s0.x) + p1*b2f(s1.x);
  float c1 = vy.y + p0*b2f(s0.y) + p1*b2f(s1.y);
  float c2 = vy.z + p0*b2f(s0.z) + p1*b2f(s1.z);
  float c3 = vy.w + p0*b2f(s0.w) + p1*b2f(s1.w);
  float ss = c0*c0 + c1*c1 + c2*c2 + c3*c3;
  __syncthreads();
  redA[tid] = ss; __syncthreads();
  for (int s = 128; s > 0; s >>= 1){
    if (tid < s) redA[tid] += redA[tid+s];
    __syncthreads();
  }
  float scale = rsqrtf(redA[0]/(float)DD + 1e-6f);
  const float* fwp = fw + tid*4;
  float o0 = c0*fwp[0]*scale, o1 = c1*fwp[1]*scale, o2 = c2*fwp[2]*scale, o3 = c3*fwp[3]*scale;
  float4 ov; ov.x = o0; ov.y = o1; ov.z = o2; ov.w = o3;
  *(float4*)&y[base] = ov;
  short4 ob; ob.x = f2b(o0); ob.y = f2b(o1); ob.z = f2b(o2); ob.w = f2b(o3);
  *(short4*)&y2bf[base] = ob;
}

// ---------------- host ----------------
extern "C" void kernel_launch(void* const* d_in, const int* in_sizes, int n_in,
                              void* d_out, int out_size, void* d_ws, size_t ws_size,
                              hipStream_t stream){
  (void)in_sizes; (void)n_in; (void)out_size; (void)ws_size;
  const float* x     = (const float*)d_in[0];
  const float* mem0  = (const float*)d_in[1];
  const float* normw = (const float*)d_in[2];
  const float* dwk   = (const float*)d_in[3];
  const float* dwb   = (const float*)d_in[4];
  const float* pw    = (const float*)d_in[5];
  const float* pwb   = (const float*)d_in[6];
  const float* Win_w = (const float*)d_in[7];
  const float* Win_b = (const float*)d_in[8];
  const float* Wf_w  = (const float*)d_in[9];
  const float* Wf_b  = (const float*)d_in[10];
  const float* Wu_w  = (const float*)d_in[11];
  const float* Wu_b  = (const float*)d_in[12];
  const float* Wo_w  = (const float*)d_in[13];
  const float* Wo_b  = (const float*)d_in[14];
  const float* rw    = (const float*)d_in[15];
  const float* rb    = (const float*)d_in[16];
  const float* e0w1  = (const float*)d_in[17];
  const float* e0b1  = (const float*)d_in[18];
  const float* e0w2  = (const float*)d_in[19];
  const float* e0b2  = (const float*)d_in[20];
  const float* e1w1  = (const float*)d_in[21];
  const float* e1b1  = (const float*)d_in[22];
  const float* e1w2  = (const float*)d_in[23];
  const float* e1b2  = (const float*)d_in[24];
  const float* fnw   = (const float*)d_in[25];
  const float* dnw   = (const float*)d_in[26];
  const float* dnb   = (const float*)d_in[27];
  const float* upw   = (const float*)d_in[28];
  const float* upb   = (const float*)d_in[29];

  char* ws = (char*)d_ws;
  size_t off = 0;
  auto alloc = [&](size_t bytes)->char*{
    char* p = ws + off; off += (bytes + 255) & ~(size_t)255; return p;
  };
  short* A2       = (short*)alloc((size_t)NROWS*2048*2);   // [xn | xc] bf16
  short* B2       = (short*)alloc((size_t)1024*2048*2);    // [Wo_x | pw] bf16
  short* W_fxuwin = (short*)alloc((size_t)768*1024*2);
  short* W_fum    = (short*)alloc((size_t)512*256*2);
  short* W_om     = (short*)alloc((size_t)1024*256*2);
  short* W_e0w1   = (short*)alloc((size_t)1024*1024*2);
  short* W_e0w2   = (short*)alloc((size_t)1024*1024*2);
  short* W_e1w1   = (short*)alloc((size_t)1024*1024*2);
  short* W_e1w2   = (short*)alloc((size_t)1024*1024*2);
  short* W_down   = (short*)alloc((size_t)256*1024*2);
  short* W_up     = (short*)alloc((size_t)1024*256*2);
  float* bias768  = (float*)alloc(768*4);
  float* bias2    = (float*)alloc(1024*4);
  float* fxu      = (float*)alloc((size_t)NROWS*768*4);
  float* ybuf     = (float*)alloc((size_t)NROWS*DD*4);
  short* m2all    = (short*)alloc((size_t)NROWS*MDD*2);
  short* ybf      = (short*)alloc((size_t)NROWS*DD*2);
  short* e0v      = (short*)alloc((size_t)NROWS*DD*2);
  short* e1v      = (short*)alloc((size_t)NROWS*DD*2);
  short* h0       = (short*)alloc((size_t)NROWS*DD*2);
  short* h1       = (short*)alloc((size_t)NROWS*DD*2);
  short* hd = m2all;   // m2all dead after G5
  short* y2bf = ybf;   // ybf dead after expert first GEMMs
  float* y2   = ybuf;  // in-place rmsnorm

  auto cvt = [&](const float* s, short* d, int rows, int cols, int ld, int o, int dld){
    int n = rows*cols;
    int blocks = (n + 255)/256; if (blocks > 4096) blocks = 4096;
    cvt_submat<<<blocks, 256, 0, stream>>>(s, d, rows, cols, ld, o, dld);
  };
  cvt(Wo_w, B2,                1024, 1024, 1280, 0,    2048);
  cvt(pw,   B2+1024,           1024, 1024, 1024, 0,    2048);
  cvt(Wf_w, W_fxuwin,           256, 1024, 1280, 0,    1024);
  cvt(Wu_w, W_fxuwin+256*1024,  256, 1024, 1280, 0,    1024);
  cvt(Win_w,W_fxuwin+512*1024,  256, 1024, 1024, 0,    1024);
  cvt(Wf_w, W_fum,              256,  256, 1280, 1024, 256);
  cvt(Wu_w, W_fum+256*256,      256,  256, 1280, 1024, 256);
  cvt(Wo_w, W_om,              1024,  256, 1280, 1024, 256);
  cvt(e0w1, W_e0w1,            1024, 1024, 1024, 0,    1024);
  cvt(e0w2, W_e0w2,            1024, 1024, 1024, 0,    1024);
  cvt(e1w1, W_e1w1,            1024, 1024, 1024, 0,    1024);
  cvt(e1w2, W_e1w2,            1024, 1024, 1024, 0,    1024);
  cvt(dnw,  W_down,             256, 1024, 1024, 0,    1024);
  cvt(upw,  W_up,              1024,  256,  256, 0,    256);
  concat3<<<3, 256, 0, stream>>>(Wf_b, 256, Wu_b, 256, Win_b, 256, bias768);
  addvec_k<<<4, 256, 0, stream>>>(Wo_b, pwb, bias2, 1024);

  rmsnorm_k<<<NROWS, 256, 0, stream>>>(x, normw, A2);
  dwconv_k<<<(NROWS*DD)/256, 256, 0, stream>>>(A2, dwk, dwb, A2);

  // G2: fxu = xn @ [Wf_x;Wu_x;Win]^T + [Wf_b;Wu_b;Win_b]   (f32)
  gemm_bt<0,0,0><<<64*6, 256, 0, stream>>>(A2, W_fxuwin, bias768, nullptr,
                                           fxu, nullptr, NROWS, 768, 1024, 2048, 6);
  // G34: ybuf = [xn|xc] @ [Wo_x|pw]^T + (Wo_b+pw_b) + x
  gemm_bt<0,0,0><<<64*8, 256, 0, stream>>>(A2, B2, bias2, x,
                                           ybuf, nullptr, NROWS, 1024, 2048, 2048, 8);
  // sequential scan (writes m2all and new_mem)
  scan_k<<<1, 512, 0, stream>>>(fxu, W_fum, mem0, m2all,
                                (float*)d_out + (size_t)NROWS*DD);
  // G5: ybuf += m2 @ Wo_m^T ; ybf = bf16(ybuf)   (permuted rows t*4+b -> b*L+t)
  gemm_bt<0,3,1><<<64*8, 256, 0, stream>>>(m2all, W_om, nullptr, nullptr,
                                           ybuf, ybf, NROWS, 1024, 256, 256, 8);
  // experts
  gemm_bt<1,2,0><<<64*8, 256, 0, stream>>>(ybf, W_e0w1, e0b1, nullptr,
                                           h0, nullptr, NROWS, 1024, 1024, 1024, 8);
  gemm_bt<1,2,0><<<64*8, 256, 0, stream>>>(ybf, W_e1w1, e1b1, nullptr,
                                           h1, nullptr, NROWS, 1024, 1024, 1024, 8);
  gemm_bt<0,2,0><<<64*8, 256, 0, stream>>>(h0, W_e0w2, e0b2, nullptr,
                                           e0v, nullptr, NROWS, 1024, 1024, 1024, 8);
  gemm_bt<0,2,0><<<64*8, 256, 0, stream>>>(h1, W_e1w2, e1b2, nullptr,
                                           e1v, nullptr, NROWS, 1024, 1024, 1024, 8);
  // router softmax + expert mix + final rmsnorm (in-place into ybuf / y2bf)
  combine_k<<<NROWS, 256, 0, stream>>>(ybuf, e0v, e1v, rw, rb, fnw, y2bf);
  // G10: hd = gelu(y2 @ down^T + down_b)   (bf16)
  gemm_bt<2,2,0><<<64*2, 256, 0, stream>>>(y2bf, W_down, dnb, nullptr,
                                           hd, nullptr, NROWS, 256, 1024, 1024, 2);
  // G11: out = hd @ up^T + up_b + y2 + resid(x)  -- add y2 and x via two adds
  gemm_bt<0,0,0><<<64*8, 256, 0, stream>>>(hd, W_up, upb, y2,
                                           (float*)d_out, nullptr, NROWS, 1024, 256, 256, 8);
  addvec_k<<<(NROWS*DD+255)/256, 256, 0, stream>>>((const float*)d_out, x,
                                                   (float*)d_out, NROWS*DD);
}

// Round 4
// 1926.718 us; speedup vs baseline: 1.6650x; 1.0875x over previous
//
#include <hip/hip_runtime.h>
#include <hip/hip_bf16.h>

#define DD 1024
#define MDD 256
#define LL 2048
#define BB 4
#define NROWS (BB*LL)   // 8192

typedef short bf16x8 __attribute__((ext_vector_type(8)));
typedef float f32x4 __attribute__((ext_vector_type(4)));

__device__ __forceinline__ short f2b(float x){
  __hip_bfloat16 h = __float2bfloat16(x);
  return *reinterpret_cast<short*>(&h);
}
__device__ __forceinline__ float b2f(short s){
  return __uint_as_float(((unsigned)(unsigned short)s) << 16);
}
__device__ __forceinline__ float frcp(float x){
#if __has_builtin(__builtin_amdgcn_rcpf)
  return __builtin_amdgcn_rcpf(x);
#else
  float r; asm("v_rcp_f32 %0, %1" : "=v"(r) : "v"(x)); return r;
#endif
}
__device__ __forceinline__ float fsigmoid(float x){
  return frcp(1.f + __expf(-x));
}
// select a[kg] without dynamic vector indexing (rule #20): 3 cndmask
__device__ __forceinline__ float sel4(f32x4 a, int kg){
  float lo = (kg & 1) ? a[1] : a[0];
  float hi = (kg & 1) ? a[3] : a[2];
  return (kg & 2) ? hi : lo;
}

// ---------------- fused weight conversion / bias prep (one launch) ----------------
// mode 0: f32 (rows,cols,sld,soff) -> bf16 dstb (dld). mode 1: f32 copy n -> dstf.
// mode 2: f32 add (src+src2) n -> dstf.
struct CvtDesc {
  const float* src; const float* src2; short* dstb; float* dstf;
  int n, cols, sld, soff, dld, mode;
};
struct CvtArgs { CvtDesc d[20]; };

__global__ __launch_bounds__(256) void cvt_all(CvtArgs a){
  int di = blockIdx.x >> 6;
  CvtDesc d = a.d[di];
  int base = (blockIdx.x & 63)*256 + threadIdx.x;
  for (int i = base; i < d.n; i += 64*256){
    int r = i / d.cols, c = i - r*d.cols;
    float v = d.src[(size_t)r*d.sld + d.soff + c];
    if (d.mode == 2) v += d.src2[i];
    if (d.mode == 0) d.dstb[(size_t)r*d.dld + c] = f2b(v);
    else             d.dstf[i] = v;
  }
}

// ---------------- rmsnorm (f32 in -> bf16 out, strided out) ----------------
__global__ __launch_bounds__(256) void rmsnorm_k(const float* __restrict__ x,
                                                 const float* __restrict__ w,
                                                 short* __restrict__ xn){
  int row = blockIdx.x, tid = threadIdx.x;
  const float* xr = x + (size_t)row*DD;
  float4 v = *(const float4*)&xr[tid*4];
  float ss = v.x*v.x + v.y*v.y + v.z*v.z + v.w*v.w;
  __shared__ float red[256];
  red[tid] = ss; __syncthreads();
  for (int s = 128; s > 0; s >>= 1){ if (tid < s) red[tid] += red[tid+s]; __syncthreads(); }
  float scale = rsqrtf(red[0]/(float)DD + 1e-6f);
  const float* wr = w + tid*4;
  short4 o;
  o.x = f2b(v.x*wr[0]*scale); o.y = f2b(v.y*wr[1]*scale);
  o.z = f2b(v.z*wr[2]*scale); o.w = f2b(v.w*wr[3]*scale);
  *(short4*)&xn[(size_t)row*2048 + tid*4] = o;
}

// ---------------- depthwise causal conv K=5 (strided in/out: A2 layout) ----------------
__global__ __launch_bounds__(256) void dwconv_k(const short* __restrict__ xnA,
                                                const float* __restrict__ dwk,
                                                const float* __restrict__ dwb,
                                                short* __restrict__ xcA){
  size_t i = (size_t)blockIdx.x*256 + threadIdx.x;  // over NROWS*DD
  int d = (int)(i & (DD-1));
  int l = (int)((i >> 10) & (LL-1));
  int b = (int)(i >> 21);
  float acc = dwb[d];
  const float* kk = dwk + d*5;
  #pragma unroll
  for (int k = 0; k < 5; ++k){
    int ll = l + k - 4;
    if (ll >= 0) acc += b2f(xnA[((size_t)(b*LL + ll))*2048 + d]) * kk[k];
  }
  xcA[((size_t)(b*LL + l))*2048 + 1024 + d] = f2b(acc);
}

// ---------------- generic bf16 MFMA GEMM: C = act(A @ Bw^T + bias) (+adds) ----------------
// A: (M,K) bf16 rows stride lda; Bw: (N,K) bf16 rows stride ldb.
// OUTMODE: 0=f32 store, 1=f32 accumulate, 2=bf16 store, 3=f32 accumulate + bf16 2nd out.
// ACT: 0 none, 1 silu, 2 exact gelu.
template<int ACT, int OUTMODE, int PERMUTE>
__global__ __launch_bounds__(256) void gemm_bt(
    const short* __restrict__ A, const short* __restrict__ Bw,
    const float* __restrict__ bias, const float* __restrict__ add0,
    const float* __restrict__ add1, void* __restrict__ Cout, short* __restrict__ Cout2,
    int M, int N, int K, int lda, int ldb, int nbn){
  __shared__ __align__(16) short As[128*32];
  __shared__ __align__(16) short Bs[128*32];
  int bm = blockIdx.x / nbn, bn = blockIdx.x % nbn;
  int tid = threadIdx.x, lane = tid & 63, w = tid >> 6;
  int wm = (w >> 1)*64, wn = (w & 1)*64;
  const int r0 = lane & 15, kg = lane >> 4;

  f32x4 acc[4][4];
  #pragma unroll
  for (int i = 0; i < 4; ++i)
    #pragma unroll
    for (int j = 0; j < 4; ++j)
      #pragma unroll
      for (int r = 0; r < 4; ++r) acc[i][j][r] = 0.f;

  const int c0 = w*64 + lane;
  const int c1 = c0 + 256;
  const short* a0 = &A [(size_t)(bm*128 + (c0 >> 2))*lda + (c0 & 3)*8];
  const short* a1 = &A [(size_t)(bm*128 + (c1 >> 2))*lda + (c1 & 3)*8];
  const short* b0 = &Bw[(size_t)(bn*128 + (c0 >> 2))*ldb + (c0 & 3)*8];
  const short* b1 = &Bw[(size_t)(bn*128 + (c1 >> 2))*ldb + (c1 & 3)*8];

  for (int k0 = 0; k0 < K; k0 += 32){
    __builtin_amdgcn_global_load_lds((const __attribute__((address_space(1))) void*)(a0 + k0),
                                     (__attribute__((address_space(3))) void*)&As[w*512], 16, 0, 0);
    __builtin_amdgcn_global_load_lds((const __attribute__((address_space(1))) void*)(b0 + k0),
                                     (__attribute__((address_space(3))) void*)&Bs[w*512], 16, 0, 0);
    __builtin_amdgcn_global_load_lds((const __attribute__((address_space(1))) void*)(a1 + k0),
                                     (__attribute__((address_space(3))) void*)&As[2048 + w*512], 16, 0, 0);
    __builtin_amdgcn_global_load_lds((const __attribute__((address_space(1))) void*)(b1 + k0),
                                     (__attribute__((address_space(3))) void*)&Bs[2048 + w*512], 16, 0, 0);
    __syncthreads();
    bf16x8 av[4], bv[4];
    #pragma unroll
    for (int i = 0; i < 4; ++i) av[i] = *(const bf16x8*)&As[(wm + i*16 + r0)*32 + kg*8];
    #pragma unroll
    for (int j = 0; j < 4; ++j) bv[j] = *(const bf16x8*)&Bs[(wn + j*16 + r0)*32 + kg*8];
    #pragma unroll
    for (int i = 0; i < 4; ++i)
      #pragma unroll
      for (int j = 0; j < 4; ++j)
        acc[i][j] = __builtin_amdgcn_mfma_f32_16x16x32_bf16(av[i], bv[j], acc[i][j], 0, 0, 0);
    __syncthreads();
  }

  #pragma unroll
  for (int i = 0; i < 4; ++i){
    int grb = bm*128 + wm + i*16 + kg*4;
    #pragma unroll
    for (int j = 0; j < 4; ++j){
      int gc = bn*128 + wn + j*16 + r0;
      float bvv = bias ? bias[gc] : 0.f;
      #pragma unroll
      for (int r = 0; r < 4; ++r){
        int gr = grb + r;
        float v = acc[i][j][r] + bvv;
        if (ACT == 1) v = v / (1.f + __expf(-v));
        else if (ACT == 2) v = 0.5f*v*(1.f + erff(v*0.70710678118f));
        size_t orow = PERMUTE ? (size_t)((gr & 3)*LL + (gr >> 2)) : (size_t)gr;
        size_t oi = orow*(size_t)N + gc;
        if (add0) v += add0[oi];
        if (add1) v += add1[oi];
        if (OUTMODE == 0) ((float*)Cout)[oi] = v;
        else if (OUTMODE == 1) ((float*)Cout)[oi] += v;
        else if (OUTMODE == 2) ((short*)Cout)[oi] = f2b(v);
        else {
          float nv = ((float*)Cout)[oi] + v;
          ((float*)Cout)[oi] = nv;
          Cout2[oi] = f2b(nv);
        }
      }
    }
  }
}

// ---------------- fused: block 0 = sequential scan; blocks 1.. = G34 GEMM ----------------
// Scan: fxu rows b*LL+t, 768 cols [fx|ux|xm_raw]; Wfu (512,256) = [Wf_m;Wu_m];
// m2all rows t*4+b. Wave w owns cols [w*32,w*32+32); lane (kg,r0): batch kg.
// G34: ybuf = [xn|xc](A2, lda 2048) @ B2^T(1024x2048) + bias2 + x, 128x128 tiles, 8 waves.
__global__ __launch_bounds__(512) void scan_g34_k(
    const float* __restrict__ fxu, const short* __restrict__ Wfu,
    const float* __restrict__ m0, short* __restrict__ m2all, float* __restrict__ newmem,
    const short* __restrict__ A2, const short* __restrict__ B2,
    const float* __restrict__ bias2, const float* __restrict__ xres,
    float* __restrict__ ybuf){
  __shared__ __align__(16) short lds[8192];   // 16KB; scan uses first 2176 shorts
  const int tid = threadIdx.x, lane = tid & 63, w = tid >> 6;
  const int r0 = lane & 15, kg = lane >> 4;

  if (blockIdx.x != 0){
    // ---------- G34 GEMM branch: 128x128 tile, 8 waves (wave = 64x32 subtile) ----------
    int bid = (int)blockIdx.x - 1;
    int bm = bid >> 3, bn = bid & 7;
    short* As = lds;          // [128][32]
    short* Bs = lds + 4096;
    int wm = (w >> 2)*64, wn = (w & 3)*32;
    f32x4 acc[4][2];
    #pragma unroll
    for (int i = 0; i < 4; ++i)
      #pragma unroll
      for (int j = 0; j < 2; ++j)
        #pragma unroll
        for (int r = 0; r < 4; ++r) acc[i][j][r] = 0.f;

    const int c = tid;  // chunk 0..511: row=c>>2, seg=c&3
    const short* ag = &A2[(size_t)(bm*128 + (c >> 2))*2048 + (c & 3)*8];
    const short* bg = &B2[(size_t)(bn*128 + (c >> 2))*2048 + (c & 3)*8];

    for (int k0 = 0; k0 < 2048; k0 += 32){
      __builtin_amdgcn_global_load_lds((const __attribute__((address_space(1))) void*)(ag + k0),
                                       (__attribute__((address_space(3))) void*)&As[w*512], 16, 0, 0);
      __builtin_amdgcn_global_load_lds((const __attribute__((address_space(1))) void*)(bg + k0),
                                       (__attribute__((address_space(3))) void*)&Bs[w*512], 16, 0, 0);
      __syncthreads();
      bf16x8 av[4], bv[2];
      #pragma unroll
      for (int i = 0; i < 4; ++i) av[i] = *(const bf16x8*)&As[(wm + i*16 + r0)*32 + kg*8];
      #pragma unroll
      for (int j = 0; j < 2; ++j) bv[j] = *(const bf16x8*)&Bs[(wn + j*16 + r0)*32 + kg*8];
      #pragma unroll
      for (int i = 0; i < 4; ++i)
        #pragma unroll
        for (int j = 0; j < 2; ++j)
          acc[i][j] = __builtin_amdgcn_mfma_f32_16x16x32_bf16(av[i], bv[j], acc[i][j], 0, 0, 0);
      __syncthreads();
    }
    #pragma unroll
    for (int i = 0; i < 4; ++i){
      int grb = bm*128 + wm + i*16 + kg*4;
      #pragma unroll
      for (int j = 0; j < 2; ++j){
        int gc = bn*128 + wn + j*16 + r0;
        float bvv = bias2[gc];
        #pragma unroll
        for (int r = 0; r < 4; ++r){
          size_t oi = (size_t)(grb + r)*1024 + gc;
          ybuf[oi] = acc[i][j][r] + bvv + xres[oi];
        }
      }
    }
    return;
  }

  // ---------- scan branch (block 0) ----------
  short* mA0 = lds;            // [4][272] x2 buffers
  short* mA1 = lds + 1088;
  const int j0 = w*32 + r0;

  bf16x8 bw[2][2][8];
  #pragma unroll
  for (int fu = 0; fu < 2; ++fu)
    #pragma unroll
    for (int p = 0; p < 2; ++p)
      #pragma unroll
      for (int kt = 0; kt < 8; ++kt)
        bw[fu][p][kt] = *(const bf16x8*)&Wfu[(size_t)(fu*256 + w*32 + p*16 + r0)*256 + kt*32 + kg*8];

  float m_reg0 = m0[kg*256 + j0];
  float m_reg1 = m0[kg*256 + j0 + 16];

  // step-t f/u raw (ready), step-t xm (ready), step-(t+1) x raw (in flight)
  float cf0, cf1, cu0, cu1, xmc0, xmc1, nx0, nx1;
  {
    size_t b0 = (size_t)kg*LL*768;
    cf0 = fxu[b0 + j0];        cf1 = fxu[b0 + j0 + 16];
    cu0 = fxu[b0 + 256 + j0];  cu1 = fxu[b0 + 256 + j0 + 16];
    float tx0 = fxu[b0 + 512 + j0], tx1 = fxu[b0 + 512 + j0 + 16];
    xmc0 = tx0*fsigmoid(tx0);  xmc1 = tx1*fsigmoid(tx1);
    size_t b1 = b0 + 768;
    nx0 = fxu[b1 + 512 + j0];  nx1 = fxu[b1 + 512 + j0 + 16];
  }
  mA0[kg*272 + j0]      = f2b(m_reg0);
  mA0[kg*272 + j0 + 16] = f2b(m_reg1);
  __syncthreads();

  for (int t = 0; t < LL; ++t){
    const short* mac = (t & 1) ? mA1 : mA0;
    short*       man = (t & 1) ? mA0 : mA1;

    bf16x8 af[8];
    #pragma unroll
    for (int kt = 0; kt < 8; ++kt)
      af[kt] = *(const bf16x8*)&mac[(r0 & 3)*272 + kt*32 + kg*8];

    // next-step xm: depends only on nx (issued >=1 full step ago) -> overlaps MFMA phase
    float xmn0 = nx0*fsigmoid(nx0);
    float xmn1 = nx1*fsigmoid(nx1);

    __builtin_amdgcn_s_setprio(1);
    f32x4 aF0 = {0.f,0.f,0.f,0.f}, aF1 = {0.f,0.f,0.f,0.f};
    f32x4 aU0 = {0.f,0.f,0.f,0.f}, aU1 = {0.f,0.f,0.f,0.f};
    #pragma unroll
    for (int kt = 0; kt < 8; ++kt){
      aF0 = __builtin_amdgcn_mfma_f32_16x16x32_bf16(af[kt], bw[0][0][kt], aF0, 0, 0, 0);
      aF1 = __builtin_amdgcn_mfma_f32_16x16x32_bf16(af[kt], bw[0][1][kt], aF1, 0, 0, 0);
      aU0 = __builtin_amdgcn_mfma_f32_16x16x32_bf16(af[kt], bw[1][0][kt], aU0, 0, 0, 0);
      aU1 = __builtin_amdgcn_mfma_f32_16x16x32_bf16(af[kt], bw[1][1][kt], aU1, 0, 0, 0);
    }
    __builtin_amdgcn_s_setprio(0);

    float gF0 = sel4(aF0, kg), gF1 = sel4(aF1, kg);
    float gU0 = sel4(aU0, kg), gU1 = sel4(aU1, kg);

    float f0 = fsigmoid(gF0 + cf0);
    float f1 = fsigmoid(gF1 + cf1);
    float u0 = fsigmoid(gU0 + cu0);
    float u1 = fsigmoid(gU1 + cu1);
    m_reg0 = f0*m_reg0 + u0*xmc0;
    m_reg1 = f1*m_reg1 + u1*xmc1;
    short mb0 = f2b(m_reg0), mb1 = f2b(m_reg1);

    m2all[(size_t)(t*4 + kg)*256 + j0]      = mb0;
    m2all[(size_t)(t*4 + kg)*256 + j0 + 16] = mb1;

    // rotate xm pipeline; prefetch f/u for t+1, x for t+2
    xmc0 = xmn0; xmc1 = xmn1;
    int t1 = (t + 1 < LL) ? t + 1 : t;
    int t2 = (t + 2 < LL) ? t + 2 : t;
    size_t bfu = ((size_t)kg*LL + t1)*768;
    size_t bx  = ((size_t)kg*LL + t2)*768;
    cf0 = fxu[bfu + j0];        cf1 = fxu[bfu + j0 + 16];
    cu0 = fxu[bfu + 256 + j0];  cu1 = fxu[bfu + 256 + j0 + 16];
    nx0 = fxu[bx + 512 + j0];   nx1 = fxu[bx + 512 + j0 + 16];

    man[kg*272 + j0]      = mb0;
    man[kg*272 + j0 + 16] = mb1;
    asm volatile("s_waitcnt lgkmcnt(0)" ::: "memory");
    __builtin_amdgcn_sched_barrier(0);
    __builtin_amdgcn_s_barrier();
    __builtin_amdgcn_sched_barrier(0);
  }

  newmem[kg*256 + j0]      = m_reg0;
  newmem[kg*256 + j0 + 16] = m_reg1;
}

// ---------------- router + expert combine + final rmsnorm ----------------
__global__ __launch_bounds__(256) void combine_k(
    float* __restrict__ y, const short* __restrict__ e0, const short* __restrict__ e1,
    const float* __restrict__ rw, const float* __restrict__ rb,
    const float* __restrict__ fw, short* __restrict__ y2bf){
  int row = blockIdx.x, tid = threadIdx.x;
  size_t base = (size_t)row*DD + tid*4;
  float4 vy = *(const float4*)&y[base];
  short4 s0 = *(const short4*)&e0[base];
  short4 s1 = *(const short4*)&e1[base];
  float4 w0 = *(const float4*)&rw[tid*4];
  float4 w1 = *(const float4*)&rw[DD + tid*4];
  float d0 = vy.x*w0.x + vy.y*w0.y + vy.z*w0.z + vy.w*w0.w;
  float d1 = vy.x*w1.x + vy.y*w1.y + vy.z*w1.z + vy.w*w1.w;
  __shared__ float redA[256], redB[256];
  redA[tid] = d0; redB[tid] = d1; __syncthreads();
  for (int s = 128; s > 0; s >>= 1){
    if (tid < s){ redA[tid] += redA[tid+s]; redB[tid] += redB[tid+s]; }
    __syncthreads();
  }
  float l0 = redA[0] + rb[0], l1 = redB[0] + rb[1];
  float p0 = 1.f/(1.f + __expf(l1 - l0));
  float p1 = 1.f - p0;
  float c0 = vy.x + p0*b2f(s0.x) + p1*b2f(s1.x);
  float c1 = vy.y + p0*b2f(s0.y) + p1*b2f(s1.y);
  float c2 = vy.z + p0*b2f(s0.z) + p1*b2f(s1.z);
  float c3 = vy.w + p0*b2f(s0.w) + p1*b2f(s1.w);
  float ss = c0*c0 + c1*c1 + c2*c2 + c3*c3;
  __syncthreads();
  redA[tid] = ss; __syncthreads();
  for (int s = 128; s > 0; s >>= 1){
    if (tid < s) redA[tid] += redA[tid+s];
    __syncthreads();
  }
  float scale = rsqrtf(redA[0]/(float)DD + 1e-6f);
  const float* fwp = fw + tid*4;
  float o0 = c0*fwp[0]*scale, o1 = c1*fwp[1]*scale, o2 = c2*fwp[2]*scale, o3 = c3*fwp[3]*scale;
  float4 ov; ov.x = o0; ov.y = o1; ov.z = o2; ov.w = o3;
  *(float4*)&y[base] = ov;
  short4 ob; ob.x = f2b(o0); ob.y = f2b(o1); ob.z = f2b(o2); ob.w = f2b(o3);
  *(short4*)&y2bf[base] = ob;
}

// ---------------- host ----------------
extern "C" void kernel_launch(void* const* d_in, const int* in_sizes, int n_in,
                              void* d_out, int out_size, void* d_ws, size_t ws_size,
                              hipStream_t stream){
  (void)in_sizes; (void)n_in; (void)out_size; (void)ws_size;
  const float* x     = (const float*)d_in[0];
  const float* mem0  = (const float*)d_in[1];
  const float* normw = (const float*)d_in[2];
  const float* dwk   = (const float*)d_in[3];
  const float* dwb   = (const float*)d_in[4];
  const float* pw    = (const float*)d_in[5];
  const float* pwb   = (const float*)d_in[6];
  const float* Win_w = (const float*)d_in[7];
  const float* Win_b = (const float*)d_in[8];
  const float* Wf_w  = (const float*)d_in[9];
  const float* Wf_b  = (const float*)d_in[10];
  const float* Wu_w  = (const float*)d_in[11];
  const float* Wu_b  = (const float*)d_in[12];
  const float* Wo_w  = (const float*)d_in[13];
  const float* Wo_b  = (const float*)d_in[14];
  const float* rw    = (const float*)d_in[15];
  const float* rb    = (const float*)d_in[16];
  const float* e0w1  = (const float*)d_in[17];
  const float* e0b1  = (const float*)d_in[18];
  const float* e0w2  = (const float*)d_in[19];
  const float* e0b2  = (const float*)d_in[20];
  const float* e1w1  = (const float*)d_in[21];
  const float* e1b1  = (const float*)d_in[22];
  const float* e1w2  = (const float*)d_in[23];
  const float* e1b2  = (const float*)d_in[24];
  const float* fnw   = (const float*)d_in[25];
  const float* dnw   = (const float*)d_in[26];
  const float* dnb   = (const float*)d_in[27];
  const float* upw   = (const float*)d_in[28];
  const float* upb   = (const float*)d_in[29];

  char* ws = (char*)d_ws;
  size_t off = 0;
  auto alloc = [&](size_t bytes)->char*{
    char* p = ws + off; off += (bytes + 255) & ~(size_t)255; return p;
  };
  short* A2       = (short*)alloc((size_t)NROWS*2048*2);   // [xn | xc] bf16
  short* B2       = (short*)alloc((size_t)1024*2048*2);    // [Wo_x | pw] bf16
  short* W_fxuwin = (short*)alloc((size_t)768*1024*2);
  short* W_fum    = (short*)alloc((size_t)512*256*2);
  short* W_om     = (short*)alloc((size_t)1024*256*2);
  short* W_e01    = (short*)alloc((size_t)2048*1024*2);    // [e0w1 ; e1w1]
  short* W_e0w2   = (short*)alloc((size_t)1024*1024*2);
  short* W_e1w2   = (short*)alloc((size_t)1024*1024*2);
  short* W_down   = (short*)alloc((size_t)256*1024*2);
  short* W_up     = (short*)alloc((size_t)1024*256*2);
  float* bias768  = (float*)alloc(768*4);
  float* bias2    = (float*)alloc(1024*4);
  float* bias01   = (float*)alloc(2048*4);
  float* fxu      = (float*)alloc((size_t)NROWS*768*4);
  float* ybuf     = (float*)alloc((size_t)NROWS*DD*4);
  short* m2all    = (short*)alloc((size_t)NROWS*MDD*2);
  short* ybf      = (short*)alloc((size_t)NROWS*DD*2);
  short* e0v      = (short*)alloc((size_t)NROWS*DD*2);
  short* e1v      = (short*)alloc((size_t)NROWS*DD*2);
  short* h01      = (short*)alloc((size_t)NROWS*2048*2);   // [h0 | h1]
  short* hd = m2all;   // m2all dead after G5
  short* y2bf = ybf;   // ybf dead after expert first GEMM
  float* y2   = ybuf;  // in-place rmsnorm

  // ---- one fused weight-conversion launch (20 descriptors x 64 blocks) ----
  CvtArgs ca;
  auto D0 = [&](const float* s, short* db, int rows, int cols, int sld, int soff, int dld){
    return CvtDesc{s, nullptr, db, nullptr, rows*cols, cols, sld, soff, dld, 0};
  };
  auto D1 = [&](const float* s, float* df, int n){
    return CvtDesc{s, nullptr, nullptr, df, n, n, 0, 0, 0, 1};
  };
  ca.d[0]  = D0(Wo_w,  B2,                1024, 1024, 1280, 0,    2048);
  ca.d[1]  = D0(pw,    B2+1024,           1024, 1024, 1024, 0,    2048);
  ca.d[2]  = D0(Wf_w,  W_fxuwin,           256, 1024, 1280, 0,    1024);
  ca.d[3]  = D0(Wu_w,  W_fxuwin+256*1024,  256, 1024, 1280, 0,    1024);
  ca.d[4]  = D0(Win_w, W_fxuwin+512*1024,  256, 1024, 1024, 0,    1024);
  ca.d[5]  = D0(Wf_w,  W_fum,              256,  256, 1280, 1024, 256);
  ca.d[6]  = D0(Wu_w,  W_fum+256*256,      256,  256, 1280, 1024, 256);
  ca.d[7]  = D0(Wo_w,  W_om,              1024,  256, 1280, 1024, 256);
  ca.d[8]  = D0(e0w1,  W_e01,             1024, 1024, 1024, 0,    1024);
  ca.d[9]  = D0(e1w1,  W_e01+1024*1024,   1024, 1024, 1024, 0,    1024);
  ca.d[10] = D0(e0w2,  W_e0w2,            1024, 1024, 1024, 0,    1024);
  ca.d[11] = D0(e1w2,  W_e1w2,            1024, 1024, 1024, 0,    1024);
  ca.d[12] = D0(dnw,   W_down,             256, 1024, 1024, 0,    1024);
  ca.d[13] = D0(upw,   W_up,              1024,  256,  256, 0,    256);
  ca.d[14] = D1(Wf_b,  bias768,       256);
  ca.d[15] = D1(Wu_b,  bias768+256,   256);
  ca.d[16] = D1(Win_b, bias768+512,   256);
  ca.d[17] = CvtDesc{Wo_b, pwb, nullptr, bias2, 1024, 1024, 0, 0, 0, 2};
  ca.d[18] = D1(e0b1,  bias01,       1024);
  ca.d[19] = D1(e1b1,  bias01+1024,  1024);
  cvt_all<<<20*64, 256, 0, stream>>>(ca);

  rmsnorm_k<<<NROWS, 256, 0, stream>>>(x, normw, A2);
  dwconv_k<<<(NROWS*DD)/256, 256, 0, stream>>>(A2, dwk, dwb, A2);

  // G2: fxu = xn @ [Wf_x;Wu_x;Win]^T + bias768   (f32)
  gemm_bt<0,0,0><<<64*6, 256, 0, stream>>>(A2, W_fxuwin, bias768, nullptr, nullptr,
                                           fxu, nullptr, NROWS, 768, 1024, 2048, 1024, 6);
  // fused: block0 = scan (m2all, newmem); blocks 1..512 = G34 (ybuf)
  scan_g34_k<<<513, 512, 0, stream>>>(fxu, W_fum, mem0, m2all,
                                      (float*)d_out + (size_t)NROWS*DD,
                                      A2, B2, bias2, x, ybuf);
  // G5: ybuf += m2 @ Wo_m^T ; ybf = bf16(ybuf)   (permuted rows t*4+b -> b*L+t)
  gemm_bt<0,3,1><<<64*8, 256, 0, stream>>>(m2all, W_om, nullptr, nullptr, nullptr,
                                           ybuf, ybf, NROWS, 1024, 256, 256, 256, 8);
  // experts stage 1 (fused): h01 = silu(ybf @ [e0w1;e1w1]^T + [e0b1;e1b1])
  gemm_bt<1,2,0><<<64*16, 256, 0, stream>>>(ybf, W_e01, bias01, nullptr, nullptr,
                                            h01, nullptr, NROWS, 2048, 1024, 1024, 1024, 16);
  // experts stage 2
  gemm_bt<0,2,0><<<64*8, 256, 0, stream>>>(h01, W_e0w2, e0b2, nullptr, nullptr,
                                           e0v, nullptr, NROWS, 1024, 1024, 2048, 1024, 8);
  gemm_bt<0,2,0><<<64*8, 256, 0, stream>>>(h01+1024, W_e1w2, e1b2, nullptr, nullptr,
                                           e1v, nullptr, NROWS, 1024, 1024, 2048, 1024, 8);
  // router softmax + expert mix + final rmsnorm (in-place into ybuf / y2bf)
  combine_k<<<NROWS, 256, 0, stream>>>(ybuf, e0v, e1v, rw, rb, fnw, y2bf);
  // G10: hd = gelu(y2 @ down^T + down_b)   (bf16)
  gemm_bt<2,2,0><<<64*2, 256, 0, stream>>>(y2bf, W_down, dnb, nullptr, nullptr,
                                           hd, nullptr, NROWS, 256, 1024, 1024, 1024, 2);
  // G11: out = hd @ up^T + up_b + y2 + x
  gemm_bt<0,0,0><<<64*8, 256, 0, stream>>>(hd, W_up, upb, y2, x,
                                           (float*)d_out, nullptr, NROWS, 1024, 256, 256, 256, 8);
}